// Round 4
// baseline (2223.366 us; speedup 1.0000x reference)
//
#include <hip/hip_runtime.h>
#include <hip/hip_bf16.h>
#include <math.h>

#define BB 8
#define NN 128
#define HH 128
#define NHD 4
#define DHD 32
#define LAY 4
#define EPSV 1e-5f

typedef __hip_bfloat16 bf16;
typedef unsigned short ushortt;

__device__ __forceinline__ float b2f(bf16 x){ return __bfloat162float(x); }
__device__ __forceinline__ bf16 f2b(float x){ return __float2bfloat16(x); }
__device__ __forceinline__ float us2f(ushortt u){ return __uint_as_float(((unsigned)u)<<16); }
__device__ __forceinline__ ushortt f2us(float x){ bf16 b=__float2bfloat16(x); return *(ushortt*)&b; }
__device__ __forceinline__ float gelu_f(float x){ return 0.5f*x*(1.0f+erff(x*0.7071067811865476f)); }

// ---------------- front end (all f32 — precision-critical for new_e) ----------------

__global__ void k_sine_eig(const float* __restrict__ e, const float* __restrict__ eigW,
                           const float* __restrict__ eigb, float* __restrict__ eig){
  int row = blockIdx.x; int tid = threadIdx.x;
  __shared__ float ee[129];
  float ev = e[row];
  if (tid < 64){
    float dv = expf(-0.1439115683121279f * (float)tid);
    float pe = ev * 100.0f * dv;
    ee[1+tid] = sinf(pe);
    ee[65+tid] = cosf(pe);
  }
  if (tid == 0) ee[0] = ev;
  __syncthreads();
  const float* wr = eigW + tid*129;
  float acc = eigb[tid];
  for (int k2=0;k2<129;k2++) acc += ee[k2]*wr[k2];
  eig[row*HH+tid] = acc;
}

__global__ void k_ln_qkv(const float* __restrict__ eig, const float* g, const float* bt,
                         const float* qkvW, const float* qkvb,
                         float* q, float* k, float* v){
  int row = blockIdx.x; int tid = threadIdx.x;
  __shared__ float buf[128]; __shared__ float xm[128];
  float x = eig[row*HH+tid];
  buf[tid]=x; __syncthreads();
  for (int s2=64;s2>0;s2>>=1){ if(tid<s2) buf[tid]+=buf[tid+s2]; __syncthreads(); }
  float mean = buf[0]*(1.0f/128.0f); __syncthreads();
  float d = x-mean; buf[tid]=d*d; __syncthreads();
  for (int s2=64;s2>0;s2>>=1){ if(tid<s2) buf[tid]+=buf[tid+s2]; __syncthreads(); }
  float var = buf[0]*(1.0f/128.0f);
  xm[tid] = d*rsqrtf(var+EPSV)*g[tid]+bt[tid];
  __syncthreads();
  float* outs[3] = {q,k,v};
  for (int s3=0;s3<3;s3++){
    const float* wr = qkvW + (s3*HH+tid)*HH;
    float acc = qkvb[s3*HH+tid];
    for (int m=0;m<HH;m++) acc += xm[m]*wr[m];
    outs[s3][row*HH+tid]=acc;
  }
}

__global__ void k_attn(const float* __restrict__ q, const float* __restrict__ k,
                       const int* __restrict__ length,
                       float* __restrict__ attnf, float* __restrict__ outp){
  int bx = blockIdx.x;
  int qi = bx & 127, hd = (bx>>7)&3, b = bx>>9;
  int tid = threadIdx.x;
  int len = length[b];
  __shared__ float qv[DHD]; __shared__ float red[128];
  if (tid < DHD) qv[tid] = q[(b*NN+qi)*HH + hd*DHD + tid];
  __syncthreads();
  float s = -1e30f;
  if (tid < len){
    const float* kr = k + (b*NN+tid)*HH + hd*DHD;
    float sc=0.f;
    for (int d2=0; d2<DHD; d2++) sc += qv[d2]*kr[d2];
    s = sc * 0.17677669529663687f; // 1/sqrt(32)
  }
  red[tid]=s; __syncthreads();
  for (int st=64;st>0;st>>=1){ if(tid<st) red[tid]=fmaxf(red[tid],red[tid+st]); __syncthreads(); }
  float mx = red[0]; __syncthreads();
  float p = (tid<len)? expf(s-mx):0.0f;
  red[tid]=p; __syncthreads();
  for (int st=64;st>0;st>>=1){ if(tid<st) red[tid]+=red[tid+st]; __syncthreads(); }
  float a = p / red[0];
  int idx = ((b*NHD+hd)*NN+qi)*NN+tid;
  attnf[idx]=a;
  outp[4104 + idx]=a;   // attn at element offset 8+4096
}

__global__ void k_ctx(const float* __restrict__ attnf, const float* __restrict__ v,
                      float* __restrict__ ctx){
  int row = blockIdx.x; // b*N+qi
  int b = row>>7, qi = row&127;
  int tid = threadIdx.x;
  int hd = tid>>5;
  const float* ar = attnf + ((b*NHD+hd)*NN+qi)*NN;
  float acc=0.f;
  for (int j=0;j<NN;j++) acc += ar[j]*v[(b*NN+j)*HH+tid];
  ctx[row*HH+tid]=acc;
}

__global__ void k_outproj(const float* __restrict__ ctx, const float* oW, const float* ob,
                          float* __restrict__ eig){
  int row=blockIdx.x, tid=threadIdx.x;
  __shared__ float c[128];
  c[tid]=ctx[row*HH+tid]; __syncthreads();
  const float* wr = oW + tid*HH;
  float acc=ob[tid];
  for (int m=0;m<HH;m++) acc += c[m]*wr[m];
  eig[row*HH+tid] += acc;
}

__global__ void k_ffn(float* __restrict__ eig, const float* g, const float* bt,
                      const float* w1, const float* b1, const float* w2, const float* b2){
  int row=blockIdx.x, tid=threadIdx.x;
  __shared__ float buf[128]; __shared__ float xm[128]; __shared__ float tt[128];
  float x = eig[row*HH+tid];
  buf[tid]=x; __syncthreads();
  for (int s2=64;s2>0;s2>>=1){ if(tid<s2) buf[tid]+=buf[tid+s2]; __syncthreads(); }
  float mean=buf[0]*(1.f/128.f); __syncthreads();
  float d=x-mean; buf[tid]=d*d; __syncthreads();
  for (int s2=64;s2>0;s2>>=1){ if(tid<s2) buf[tid]+=buf[tid+s2]; __syncthreads(); }
  float var=buf[0]*(1.f/128.f);
  xm[tid]=d*rsqrtf(var+EPSV)*g[tid]+bt[tid];
  __syncthreads();
  const float* wr1=w1+tid*HH;
  float a1=b1[tid];
  for (int m=0;m<HH;m++) a1+=xm[m]*wr1[m];
  tt[tid]=gelu_f(a1); __syncthreads();
  const float* wr2=w2+tid*HH;
  float a2=b2[tid];
  for (int m=0;m<HH;m++) a2+=tt[m]*wr2[m];
  eig[row*HH+tid]=x+a2;
}

__global__ void k_dec(const float* __restrict__ eig, const float* dW, const float* db,
                      float* __restrict__ newe, float* __restrict__ outp){
  int b = blockIdx.x, n = threadIdx.x;
  __shared__ float w[NHD*HH];
  for (int i=n;i<NHD*HH;i+=128) w[i]=dW[i];
  __syncthreads();
  float acc[NHD];
  #pragma unroll
  for (int kk=0;kk<NHD;kk++) acc[kk]=db[kk];
  const float* er = eig + (b*NN+n)*HH;
  for (int h2=0;h2<HH;h2++){
    float ev = er[h2];
    #pragma unroll
    for (int kk=0;kk<NHD;kk++) acc[kk]+=ev*w[kk*HH+h2];
  }
  #pragma unroll
  for (int kk=0;kk<NHD;kk++){
    int idx=(b*NHD+kk)*NN+n; newe[idx]=acc[kk];
    outp[8 + idx]=acc[kk];  // new_e at element offset 8
  }
}

// ---------------- bases (bf16 staging ok: feeds h only, loose threshold) ----------------

__global__ void k_filters(const float* __restrict__ u, const float* __restrict__ newe,
                          float* __restrict__ filt){
  int b = blockIdx.x, n0 = blockIdx.y*16, p0 = blockIdx.z*16;
  int tx = threadIdx.x, ty = threadIdx.y; int tid = ty*16+tx;
  __shared__ float un[16][17], upt[16][17], wk[4][16];
  float acc[4]={0.f,0.f,0.f,0.f};
  for (int mt=0; mt<8; mt++){
    __syncthreads();
    un[ty][tx]  = u[(b*NN+n0+ty)*NN + mt*16+tx];
    upt[tx][ty] = u[(b*NN+p0+ty)*NN + mt*16+tx];
    if (tid<64) wk[tid>>4][tid&15] = newe[(b*NHD+(tid>>4))*NN + mt*16 + (tid&15)];
    __syncthreads();
    #pragma unroll
    for (int mm=0;mm<16;mm++){
      float pr = un[ty][mm]*upt[mm][tx];
      #pragma unroll
      for (int kk=0;kk<4;kk++) acc[kk] += pr*wk[kk][mm];
    }
  }
  float4 o; o.x=acc[0];o.y=acc[1];o.z=acc[2];o.w=acc[3];
  *(float4*)&filt[((b*NN+n0+ty)*NN+p0+tx)*4] = o;
}

__global__ __launch_bounds__(256) void k_fe(const float* __restrict__ filt,
    const float* __restrict__ w1g, const float* __restrict__ b1g,
    const float* __restrict__ w2g, const float* __restrict__ b2g,
    bf16* __restrict__ bases){
  int r0 = blockIdx.x * 16;            // 16 edge rows, same (b,n)
  int n  = (r0 >> 7) & 127;
  int p0 = r0 & 127;
  int tid = threadIdx.x;
  __shared__ alignas(16) ushortt w2[128*132];   // bf16 weights, stride 132 (8B-aligned, 2-way alias = free)
  __shared__ alignas(16) float t[16][128];      // 16B-aligned rows; reads are lane-broadcast
  __shared__ float in5[16][5];
  __shared__ float w1[640], b1s[128], b2s[128];
  for (int idx=tid; idx<16384; idx+=256){ int h2=idx>>7, m=idx&127; w2[h2*132+m]=f2us(w2g[idx]); }
  for (int idx=tid; idx<640; idx+=256) w1[idx]=w1g[idx];
  if (tid<128){ b1s[tid]=b1g[tid]; b2s[tid]=b2g[tid]; }
  if (tid<64){ int il=tid>>2, kk=tid&3; in5[il][1+kk]=filt[(r0+il)*4+kk]; }
  if (tid<16) in5[tid][0] = ((p0+tid)==n)?1.0f:0.0f;
  __syncthreads();
  for (int idx=tid; idx<2048; idx+=256){ int il=idx>>7, m=idx&127;
    float a = b1s[m];
    #pragma unroll
    for (int j=0;j<5;j++) a += w1[m*5+j]*in5[il][j];
    t[il][m]=gelu_f(a);
  }
  __syncthreads();
  int h2 = tid&127, rg = tid>>7;
  for (int c=0;c<2;c++){
    int ilb = c*8+rg*4;
    float acc0=0.f,acc1=0.f,acc2=0.f,acc3=0.f;
    for (int m=0;m<128;m+=4){
      ushort4 wu = *(const ushort4*)&w2[h2*132+m];
      float wa=us2f(wu.x), wb=us2f(wu.y), wc=us2f(wu.z), wd=us2f(wu.w);
      float4 sa=*(const float4*)&t[ilb+0][m];
      float4 sb=*(const float4*)&t[ilb+1][m];
      float4 sc=*(const float4*)&t[ilb+2][m];
      float4 sd=*(const float4*)&t[ilb+3][m];
      acc0+=wa*sa.x+wb*sa.y+wc*sa.z+wd*sa.w;
      acc1+=wa*sb.x+wb*sb.y+wc*sb.z+wd*sb.w;
      acc2+=wa*sc.x+wb*sc.y+wc*sc.z+wd*sc.w;
      acc3+=wa*sd.x+wb*sd.y+wc*sd.z+wd*sd.w;
    }
    float bb = b2s[h2];
    bases[(r0+ilb+0)*HH + h2] = f2b(gelu_f(acc0+bb));
    bases[(r0+ilb+1)*HH + h2] = f2b(gelu_f(acc1+bb));
    bases[(r0+ilb+2)*HH + h2] = f2b(gelu_f(acc2+bb));
    bases[(r0+ilb+3)*HH + h2] = f2b(gelu_f(acc3+bb));
  }
}

// ---------------- message passing ----------------

__global__ void k_xfinit(const float* __restrict__ aemb, const int* __restrict__ nf,
                         float* __restrict__ xf){
  int idx = blockIdx.x*256+threadIdx.x;
  int node = idx >> 7, h2 = idx & 127;
  xf[idx] = aemb[nf[node]*HH + h2];
}

__global__ __launch_bounds__(256) void k_pre(const float* __restrict__ xfin, float* __restrict__ xfout,
    const bf16* __restrict__ bases, const float* __restrict__ bemb,
    const int* __restrict__ ef, const int* __restrict__ length,
    const float* __restrict__ wg, const float* __restrict__ bg){
  int bj = blockIdx.x; int b = bj>>7, j = bj&127;
  int len = length[b];
  int tid = threadIdx.x; int h2 = tid&127; int rg = tid>>7;
  __shared__ alignas(16) ushortt wlds[128*132];
  __shared__ alignas(16) float s[8][128];
  __shared__ float part[2][128];
  for (int idx=tid; idx<16384; idx+=256){ int hh=idx>>7, m=idx&127; wlds[hh*132+m]=f2us(wg[idx]); }
  float pb = bg[h2];
  float agg = 0.0f;
  __syncthreads();
  if (j < len){
    for (int i0=0;i0<len;i0+=8){
      for (int idx=tid; idx<1024; idx+=256){ int il=idx>>7, m=idx&127; int i=i0+il;
        float val=0.0f;
        if (i<len){
          int e2 = ef[(b*NN+i)*NN+j];
          val = xfin[(b*NN+i)*HH+m] + bemb[e2*HH+m];
        }
        s[il][m]=val;
      }
      __syncthreads();
      int ilb = rg*4;
      float acc0=0.f,acc1=0.f,acc2=0.f,acc3=0.f;
      for (int m=0;m<128;m+=4){
        ushort4 wv = *(const ushort4*)&wlds[h2*132+m];
        float wa=us2f(wv.x), wb=us2f(wv.y), wc=us2f(wv.z), wd=us2f(wv.w);
        float4 sa=*(const float4*)&s[ilb+0][m];
        float4 sb=*(const float4*)&s[ilb+1][m];
        float4 sc=*(const float4*)&s[ilb+2][m];
        float4 sd=*(const float4*)&s[ilb+3][m];
        acc0+=wa*sa.x+wb*sa.y+wc*sa.z+wd*sa.w;
        acc1+=wa*sb.x+wb*sb.y+wc*sb.z+wd*sb.w;
        acc2+=wa*sc.x+wb*sc.y+wc*sc.z+wd*sc.w;
        acc3+=wa*sd.x+wb*sd.y+wc*sd.z+wd*sd.w;
      }
      float accs[4]={acc0,acc1,acc2,acc3};
      #pragma unroll
      for (int r=0;r<4;r++){
        int i = i0+ilb+r;
        if (i<len){
          float msg = gelu_f(accs[r]+pb)*b2f(bases[((b*NN+i)*NN+j)*HH+h2]);
          agg += msg;
        }
      }
      __syncthreads();
    }
  }
  part[rg][h2]=agg; __syncthreads();
  if (tid<128){
    float a = part[0][tid]+part[1][tid];
    xfout[(b*NN+j)*HH+tid] = xfin[(b*NN+j)*HH+tid] + a;
  }
}

__global__ void k_g1(const float* __restrict__ xf, const float* w, const float* bias,
                     float* __restrict__ t1){
  int row=blockIdx.x, tid=threadIdx.x;
  __shared__ float xr[128];
  xr[tid]=xf[row*HH+tid]; __syncthreads();
  const float* wr = w + tid*HH;
  float acc=bias[tid];
  for (int m=0;m<HH;m++) acc+=xr[m]*wr[m];
  t1[row*HH+tid]=acc;
}

__global__ void k_bnstats(const float* __restrict__ t, const int* __restrict__ length,
                          float* __restrict__ meano, float* __restrict__ istdo){
  int f = blockIdx.x, tid = threadIdx.x;
  __shared__ float s1[256], s2[256];
  float a=0.f, a2=0.f;
  for (int r=tid;r<BB*NN;r+=256){ int b=r>>7, n=r&127;
    if (n < length[b]){ float x = t[r*HH+f]; a+=x; a2+=x*x; } }
  s1[tid]=a; s2[tid]=a2; __syncthreads();
  for (int st=128;st>0;st>>=1){ if(tid<st){ s1[tid]+=s1[tid+st]; s2[tid]+=s2[tid+st]; } __syncthreads(); }
  if (tid==0){
    float cnt=0.f; for (int b=0;b<BB;b++) cnt += (float)length[b];
    float mu = s1[0]/cnt; float var = s2[0]/cnt - mu*mu;
    meano[f]=mu; istdo[f]=rsqrtf(fmaxf(var,0.0f)+EPSV);
  }
}

__global__ void k_g2(const float* __restrict__ t1, const float* mean1, const float* istd1,
                     const float* g1, const float* bb1, const float* w2, const float* bias2,
                     float* __restrict__ t2){
  int row=blockIdx.x, tid=threadIdx.x;
  __shared__ float yr[128];
  float x = t1[row*HH+tid];
  float y = (x-mean1[tid])*istd1[tid]*g1[tid]+bb1[tid];
  yr[tid] = fmaxf(y,0.0f); __syncthreads();
  const float* wr = w2 + tid*HH;
  float acc=bias2[tid];
  for (int m=0;m<HH;m++) acc+=yr[m]*wr[m];
  t2[row*HH+tid]=acc;
}

__global__ void k_apply(const float* __restrict__ t2, const float* mean2, const float* istd2,
                        const float* g2, const float* bb2, float* __restrict__ xf){
  int idx = blockIdx.x*256+threadIdx.x;
  int f = idx & 127;
  float x = t2[idx];
  float y = (x-mean2[f])*istd2[f]*g2[f]+bb2[f];
  xf[idx] += fmaxf(y,0.0f);
}

__global__ void k_pool(const float* __restrict__ xf, const int* __restrict__ length,
                       const float* lw, const float* lb, float* __restrict__ outp){
  int b = blockIdx.x, tid=threadIdx.x;
  int len = length[b];
  float s=0.f;
  for (int n2=0;n2<len;n2++) s += xf[(b*NN+n2)*HH+tid];
  s /= (float)len;
  __shared__ float red[128];
  red[tid]=s*lw[tid]; __syncthreads();
  for (int st=64;st>0;st>>=1){ if(tid<st) red[tid]+=red[tid+st]; __syncthreads(); }
  if (tid==0) outp[b]=red[0]+lb[0];
}

// ---------------- host ----------------

extern "C" void kernel_launch(void* const* d_in, const int* in_sizes, int n_in,
                              void* d_out, int out_size, void* d_ws, size_t ws_size,
                              hipStream_t stream) {
  (void)in_sizes; (void)n_in; (void)out_size; (void)ws_size;
  const float* e        = (const float*)d_in[0];
  const float* u        = (const float*)d_in[1];
  const float* atom_emb = (const float*)d_in[2];
  const float* bond_emb = (const float*)d_in[3];
  const float* eigw_W   = (const float*)d_in[4];
  const float* eigw_b   = (const float*)d_in[5];
  const float* mng      = (const float*)d_in[6];
  const float* mnb      = (const float*)d_in[7];
  const float* qkvW     = (const float*)d_in[8];
  const float* qkvb     = (const float*)d_in[9];
  const float* outW     = (const float*)d_in[10];
  const float* outb     = (const float*)d_in[11];
  const float* fng      = (const float*)d_in[12];
  const float* fnb      = (const float*)d_in[13];
  const float* ffn1W    = (const float*)d_in[14];
  const float* ffn1b    = (const float*)d_in[15];
  const float* ffn2W    = (const float*)d_in[16];
  const float* ffn2b    = (const float*)d_in[17];
  const float* decW     = (const float*)d_in[18];
  const float* decb     = (const float*)d_in[19];
  const float* fe1W     = (const float*)d_in[20];
  const float* fe1b     = (const float*)d_in[21];
  const float* fe2W     = (const float*)d_in[22];
  const float* fe2b     = (const float*)d_in[23];
  const float* preW     = (const float*)d_in[24];
  const float* preb     = (const float*)d_in[25];
  const float* f1W      = (const float*)d_in[26];
  const float* f1b      = (const float*)d_in[27];
  const float* bn1g     = (const float*)d_in[28];
  const float* bn1b     = (const float*)d_in[29];
  const float* f2W      = (const float*)d_in[30];
  const float* f2b      = (const float*)d_in[31];
  const float* bn2g     = (const float*)d_in[32];
  const float* bn2b     = (const float*)d_in[33];
  const float* linW     = (const float*)d_in[34];
  const float* linb     = (const float*)d_in[35];
  const int* nodef      = (const int*)d_in[36];
  const int* edgef      = (const int*)d_in[37];
  const int* length     = (const int*)d_in[38];

  float* outp = (float*)d_out;   // h[8] ++ new_e[4096] ++ attn[524288], f32

  char* p = (char*)d_ws;
  auto alloc = [&](size_t bytes)->void*{ void* r=(void*)p; p += (bytes+255)&~(size_t)255; return r; };
  const int TOK = BB*NN*HH;           // 131072
  float* eig   = (float*)alloc(TOK*4);
  float* q     = (float*)alloc(TOK*4);
  float* k     = (float*)alloc(TOK*4);
  float* v     = (float*)alloc(TOK*4);
  float* attnf = (float*)alloc((size_t)BB*NHD*NN*NN*4);
  float* ctx   = (float*)alloc(TOK*4);
  float* newe  = (float*)alloc(BB*NHD*NN*4);
  float* filt  = (float*)alloc((size_t)BB*NN*NN*4*4);
  bf16*  bases = (bf16*) alloc((size_t)BB*NN*NN*HH*2);
  float* xf0   = (float*)alloc(TOK*4);
  float* xf1   = (float*)alloc(TOK*4);
  float* t1    = (float*)alloc(TOK*4);
  float* t2    = (float*)alloc(TOK*4);
  float* mean1 = (float*)alloc(128*4);
  float* istd1 = (float*)alloc(128*4);
  float* mean2 = (float*)alloc(128*4);
  float* istd2 = (float*)alloc(128*4);

  // front end
  k_sine_eig<<<BB*NN, 128, 0, stream>>>(e, eigw_W, eigw_b, eig);
  k_ln_qkv<<<BB*NN, 128, 0, stream>>>(eig, mng, mnb, qkvW, qkvb, q, k, v);
  k_attn<<<BB*NHD*NN, 128, 0, stream>>>(q, k, length, attnf, outp);
  k_ctx<<<BB*NN, 128, 0, stream>>>(attnf, v, ctx);
  k_outproj<<<BB*NN, 128, 0, stream>>>(ctx, outW, outb, eig);
  k_ffn<<<BB*NN, 128, 0, stream>>>(eig, fng, fnb, ffn1W, ffn1b, ffn2W, ffn2b);
  k_dec<<<BB, 128, 0, stream>>>(eig, decW, decb, newe, outp);

  // bases
  k_filters<<<dim3(BB,8,8), dim3(16,16), 0, stream>>>(u, newe, filt);
  k_fe<<<(BB*NN*NN)/16, 256, 0, stream>>>(filt, fe1W, fe1b, fe2W, fe2b, bases);

  // message passing
  k_xfinit<<<TOK/256, 256, 0, stream>>>(atom_emb, nodef, xf0);
  float* src = xf0; float* dst = xf1;
  for (int l=0;l<LAY;l++){
    k_pre<<<BB*NN, 256, 0, stream>>>(src, dst, bases, bond_emb, edgef, length,
                                     preW + (size_t)l*HH*HH, preb + l*HH);
    k_g1<<<BB*NN, 128, 0, stream>>>(dst, f1W + (size_t)l*HH*HH, f1b + l*HH, t1);
    k_bnstats<<<128, 256, 0, stream>>>(t1, length, mean1, istd1);
    k_g2<<<BB*NN, 128, 0, stream>>>(t1, mean1, istd1, bn1g + l*HH, bn1b + l*HH,
                                    f2W + (size_t)l*HH*HH, f2b + l*HH, t2);
    k_bnstats<<<128, 256, 0, stream>>>(t2, length, mean2, istd2);
    k_apply<<<TOK/256, 256, 0, stream>>>(t2, mean2, istd2, bn2g + l*HH, bn2b + l*HH, dst);
    float* tmp = src; src = dst; dst = tmp;
  }
  // after loop final xf is in src (xf0)
  k_pool<<<BB, 128, 0, stream>>>(src, length, linW, linb, outp);
}

// Round 5
// 647.998 us; speedup vs baseline: 3.4311x; 3.4311x over previous
//
#include <hip/hip_runtime.h>
#include <hip/hip_bf16.h>
#include <math.h>

#define BB 8
#define NN 128
#define HH 128
#define NHD 4
#define DHD 32
#define LAY 4
#define EPSV 1e-5f

typedef __hip_bfloat16 bf16;
typedef unsigned short ushortt;
typedef short bf16x8 __attribute__((ext_vector_type(8)));
typedef float f32x4 __attribute__((ext_vector_type(4)));

__device__ __forceinline__ float b2f(bf16 x){ return __bfloat162float(x); }
__device__ __forceinline__ bf16 f2b(float x){ return __float2bfloat16(x); }
__device__ __forceinline__ float us2f(ushortt u){ return __uint_as_float(((unsigned)u)<<16); }
__device__ __forceinline__ ushortt f2us(float x){ bf16 b=__float2bfloat16(x); return *(ushortt*)&b; }
__device__ __forceinline__ float gelu_f(float x){ return 0.5f*x*(1.0f+erff(x*0.7071067811865476f)); }

// ---------------- front end (all f32 — precision-critical for new_e) ----------------

__global__ void k_sine_eig(const float* __restrict__ e, const float* __restrict__ eigW,
                           const float* __restrict__ eigb, float* __restrict__ eig){
  int row = blockIdx.x; int tid = threadIdx.x;
  __shared__ float ee[129];
  float ev = e[row];
  if (tid < 64){
    float dv = expf(-0.1439115683121279f * (float)tid);
    float pe = ev * 100.0f * dv;
    ee[1+tid] = sinf(pe);
    ee[65+tid] = cosf(pe);
  }
  if (tid == 0) ee[0] = ev;
  __syncthreads();
  const float* wr = eigW + tid*129;
  float acc = eigb[tid];
  for (int k2=0;k2<129;k2++) acc += ee[k2]*wr[k2];
  eig[row*HH+tid] = acc;
}

__global__ void k_ln_qkv(const float* __restrict__ eig, const float* g, const float* bt,
                         const float* qkvW, const float* qkvb,
                         float* q, float* k, float* v){
  int row = blockIdx.x; int tid = threadIdx.x;
  __shared__ float buf[128]; __shared__ float xm[128];
  float x = eig[row*HH+tid];
  buf[tid]=x; __syncthreads();
  for (int s2=64;s2>0;s2>>=1){ if(tid<s2) buf[tid]+=buf[tid+s2]; __syncthreads(); }
  float mean = buf[0]*(1.0f/128.0f); __syncthreads();
  float d = x-mean; buf[tid]=d*d; __syncthreads();
  for (int s2=64;s2>0;s2>>=1){ if(tid<s2) buf[tid]+=buf[tid+s2]; __syncthreads(); }
  float var = buf[0]*(1.0f/128.0f);
  xm[tid] = d*rsqrtf(var+EPSV)*g[tid]+bt[tid];
  __syncthreads();
  float* outs[3] = {q,k,v};
  for (int s3=0;s3<3;s3++){
    const float* wr = qkvW + (s3*HH+tid)*HH;
    float acc = qkvb[s3*HH+tid];
    for (int m=0;m<HH;m++) acc += xm[m]*wr[m];
    outs[s3][row*HH+tid]=acc;
  }
}

__global__ void k_attn(const float* __restrict__ q, const float* __restrict__ k,
                       const int* __restrict__ length,
                       float* __restrict__ attnf, float* __restrict__ outp){
  int bx = blockIdx.x;
  int qi = bx & 127, hd = (bx>>7)&3, b = bx>>9;
  int tid = threadIdx.x;
  int len = length[b];
  __shared__ float qv[DHD]; __shared__ float red[128];
  if (tid < DHD) qv[tid] = q[(b*NN+qi)*HH + hd*DHD + tid];
  __syncthreads();
  float s = -1e30f;
  if (tid < len){
    const float* kr = k + (b*NN+tid)*HH + hd*DHD;
    float sc=0.f;
    for (int d2=0; d2<DHD; d2++) sc += qv[d2]*kr[d2];
    s = sc * 0.17677669529663687f; // 1/sqrt(32)
  }
  red[tid]=s; __syncthreads();
  for (int st=64;st>0;st>>=1){ if(tid<st) red[tid]=fmaxf(red[tid],red[tid+st]); __syncthreads(); }
  float mx = red[0]; __syncthreads();
  float p = (tid<len)? expf(s-mx):0.0f;
  red[tid]=p; __syncthreads();
  for (int st=64;st>0;st>>=1){ if(tid<st) red[tid]+=red[tid+st]; __syncthreads(); }
  float a = p / red[0];
  int idx = ((b*NHD+hd)*NN+qi)*NN+tid;
  attnf[idx]=a;
  outp[4104 + idx]=a;   // attn at element offset 8+4096
}

__global__ void k_ctx(const float* __restrict__ attnf, const float* __restrict__ v,
                      float* __restrict__ ctx){
  int row = blockIdx.x; // b*N+qi
  int b = row>>7, qi = row&127;
  int tid = threadIdx.x;
  int hd = tid>>5;
  const float* ar = attnf + ((b*NHD+hd)*NN+qi)*NN;
  float acc=0.f;
  for (int j=0;j<NN;j++) acc += ar[j]*v[(b*NN+j)*HH+tid];
  ctx[row*HH+tid]=acc;
}

__global__ void k_outproj(const float* __restrict__ ctx, const float* oW, const float* ob,
                          float* __restrict__ eig){
  int row=blockIdx.x, tid=threadIdx.x;
  __shared__ float c[128];
  c[tid]=ctx[row*HH+tid]; __syncthreads();
  const float* wr = oW + tid*HH;
  float acc=ob[tid];
  for (int m=0;m<HH;m++) acc += c[m]*wr[m];
  eig[row*HH+tid] += acc;
}

__global__ void k_ffn(float* __restrict__ eig, const float* g, const float* bt,
                      const float* w1, const float* b1, const float* w2, const float* b2){
  int row=blockIdx.x, tid=threadIdx.x;
  __shared__ float buf[128]; __shared__ float xm[128]; __shared__ float tt[128];
  float x = eig[row*HH+tid];
  buf[tid]=x; __syncthreads();
  for (int s2=64;s2>0;s2>>=1){ if(tid<s2) buf[tid]+=buf[tid+s2]; __syncthreads(); }
  float mean=buf[0]*(1.f/128.f); __syncthreads();
  float d=x-mean; buf[tid]=d*d; __syncthreads();
  for (int s2=64;s2>0;s2>>=1){ if(tid<s2) buf[tid]+=buf[tid+s2]; __syncthreads(); }
  float var=buf[0]*(1.f/128.f);
  xm[tid]=d*rsqrtf(var+EPSV)*g[tid]+bt[tid];
  __syncthreads();
  const float* wr1=w1+tid*HH;
  float a1=b1[tid];
  for (int m=0;m<HH;m++) a1+=xm[m]*wr1[m];
  tt[tid]=gelu_f(a1); __syncthreads();
  const float* wr2=w2+tid*HH;
  float a2=b2[tid];
  for (int m=0;m<HH;m++) a2+=tt[m]*wr2[m];
  eig[row*HH+tid]=x+a2;
}

__global__ void k_dec(const float* __restrict__ eig, const float* dW, const float* db,
                      float* __restrict__ newe, float* __restrict__ outp){
  int b = blockIdx.x, n = threadIdx.x;
  __shared__ float w[NHD*HH];
  for (int i=n;i<NHD*HH;i+=128) w[i]=dW[i];
  __syncthreads();
  float acc[NHD];
  #pragma unroll
  for (int kk=0;kk<NHD;kk++) acc[kk]=db[kk];
  const float* er = eig + (b*NN+n)*HH;
  for (int h2=0;h2<HH;h2++){
    float ev = er[h2];
    #pragma unroll
    for (int kk=0;kk<NHD;kk++) acc[kk]+=ev*w[kk*HH+h2];
  }
  #pragma unroll
  for (int kk=0;kk<NHD;kk++){
    int idx=(b*NHD+kk)*NN+n; newe[idx]=acc[kk];
    outp[8 + idx]=acc[kk];  // new_e at element offset 8
  }
}

// ---------------- bases ----------------

__global__ void k_filters(const float* __restrict__ u, const float* __restrict__ newe,
                          float* __restrict__ filt){
  int b = blockIdx.x, n0 = blockIdx.y*16, p0 = blockIdx.z*16;
  int tx = threadIdx.x, ty = threadIdx.y; int tid = ty*16+tx;
  __shared__ float un[16][17], upt[16][17], wk[4][16];
  float acc[4]={0.f,0.f,0.f,0.f};
  for (int mt=0; mt<8; mt++){
    __syncthreads();
    un[ty][tx]  = u[(b*NN+n0+ty)*NN + mt*16+tx];
    upt[tx][ty] = u[(b*NN+p0+ty)*NN + mt*16+tx];
    if (tid<64) wk[tid>>4][tid&15] = newe[(b*NHD+(tid>>4))*NN + mt*16 + (tid&15)];
    __syncthreads();
    #pragma unroll
    for (int mm=0;mm<16;mm++){
      float pr = un[ty][mm]*upt[mm][tx];
      #pragma unroll
      for (int kk=0;kk<4;kk++) acc[kk] += pr*wk[kk][mm];
    }
  }
  float4 o; o.x=acc[0];o.y=acc[1];o.z=acc[2];o.w=acc[3];
  *(float4*)&filt[((b*NN+n0+ty)*NN+p0+tx)*4] = o;
}

// convert fe2W (16384) + preW (4*16384) to bf16 once
__global__ void k_cvtw(const float* __restrict__ fe2W, const float* __restrict__ preW,
                       ushortt* __restrict__ wbf){
  int idx = blockIdx.x*256 + threadIdx.x;
  if (idx >= 81920) return;
  float v = (idx < 16384) ? fe2W[idx] : preW[idx - 16384];
  wbf[idx] = f2us(v);
}

// fused: t = gelu(in5 @ fe1W^T + b1) -> LDS bf16 ; bases = gelu(t @ fe2W^T + b2) via MFMA
__global__ __launch_bounds__(256) void k_fe2(const float* __restrict__ filt,
    const float* __restrict__ w1g, const float* __restrict__ b1g,
    const ushortt* __restrict__ w2bf, const float* __restrict__ b2g,
    bf16* __restrict__ bases){
  int bi = blockIdx.x;            // b*128 + n
  int nloc = bi & 127;
  int tid = threadIdx.x;
  int lane = tid & 63, w = tid >> 6, quad = lane >> 4, l15 = lane & 15;
  __shared__ alignas(16) ushortt sA[128*136];
  __shared__ float4 sF[128];
  __shared__ float w1[640], b1s[128], b2s[128];
  if (tid < 128) sF[tid] = ((const float4*)filt)[bi*128 + tid];
  for (int i = tid; i < 640; i += 256) w1[i] = w1g[i];
  if (tid < 128){ b1s[tid] = b1g[tid]; b2s[tid] = b2g[tid]; }
  __syncthreads();
  for (int idx = tid; idx < 4096; idx += 256){
    int row = idx >> 5, m0 = (idx & 31) * 4;
    float dg = (row == nloc) ? 1.0f : 0.0f;
    float4 f4 = sF[row];
    ushort4 o;
    {
      float a0 = b1s[m0+0] + w1[(m0+0)*5]*dg + w1[(m0+0)*5+1]*f4.x + w1[(m0+0)*5+2]*f4.y + w1[(m0+0)*5+3]*f4.z + w1[(m0+0)*5+4]*f4.w;
      float a1 = b1s[m0+1] + w1[(m0+1)*5]*dg + w1[(m0+1)*5+1]*f4.x + w1[(m0+1)*5+2]*f4.y + w1[(m0+1)*5+3]*f4.z + w1[(m0+1)*5+4]*f4.w;
      float a2 = b1s[m0+2] + w1[(m0+2)*5]*dg + w1[(m0+2)*5+1]*f4.x + w1[(m0+2)*5+2]*f4.y + w1[(m0+2)*5+3]*f4.z + w1[(m0+2)*5+4]*f4.w;
      float a3 = b1s[m0+3] + w1[(m0+3)*5]*dg + w1[(m0+3)*5+1]*f4.x + w1[(m0+3)*5+2]*f4.y + w1[(m0+3)*5+3]*f4.z + w1[(m0+3)*5+4]*f4.w;
      o.x = f2us(gelu_f(a0)); o.y = f2us(gelu_f(a1)); o.z = f2us(gelu_f(a2)); o.w = f2us(gelu_f(a3));
    }
    *(ushort4*)&sA[row*136 + m0] = o;
  }
  __syncthreads();
  f32x4 acc[2][8];
  #pragma unroll
  for (int mt=0;mt<2;mt++)
    #pragma unroll
    for (int nt=0;nt<8;nt++) acc[mt][nt] = (f32x4){0.f,0.f,0.f,0.f};
  #pragma unroll
  for (int kk = 0; kk < 128; kk += 32){
    bf16x8 af[2], bfr[8];
    #pragma unroll
    for (int mt=0;mt<2;mt++) af[mt] = *(const bf16x8*)&sA[(w*32+mt*16+l15)*136 + kk + quad*8];
    #pragma unroll
    for (int nt=0;nt<8;nt++) bfr[nt] = *(const bf16x8*)&w2bf[(nt*16+l15)*128 + kk + quad*8];
    #pragma unroll
    for (int mt=0;mt<2;mt++)
      #pragma unroll
      for (int nt=0;nt<8;nt++)
        acc[mt][nt] = __builtin_amdgcn_mfma_f32_16x16x32_bf16(af[mt], bfr[nt], acc[mt][nt], 0, 0, 0);
  }
  #pragma unroll
  for (int mt=0;mt<2;mt++)
    #pragma unroll
    for (int nt=0;nt<8;nt++){
      int h = nt*16 + l15;
      float bb = b2s[h];
      #pragma unroll
      for (int reg=0;reg<4;reg++){
        int pr = w*32 + mt*16 + quad*4 + reg;
        bases[((size_t)bi*128 + pr)*128 + h] = f2b(gelu_f(acc[mt][nt][reg] + bb));
      }
    }
}

// ---------------- message passing ----------------

__global__ void k_xfinit(const float* __restrict__ aemb, const int* __restrict__ nf,
                         float* __restrict__ xf){
  int idx = blockIdx.x*256+threadIdx.x;
  int node = idx >> 7, h2 = idx & 127;
  xf[idx] = aemb[nf[node]*HH + h2];
}

// MFMA message passing: per block (b,j): s = xf[i]+bemb[ef[i][j]] (bf16 LDS),
// msg = gelu(s @ preW^T + pb) * bases[:,j,:], agg over i -> xfout[j]
__global__ __launch_bounds__(256) void k_pre2(const float* __restrict__ xfin, float* __restrict__ xfout,
    const bf16* __restrict__ bases, const float* __restrict__ bemb,
    const int* __restrict__ ef, const int* __restrict__ length,
    const ushortt* __restrict__ wbf, const float* __restrict__ bg){
  int bj = blockIdx.x; int b = bj >> 7, j = bj & 127;
  int len = length[b];
  int tid = threadIdx.x;
  int lane = tid & 63, w = tid >> 6, quad = lane >> 4, l15 = lane & 15;
  __shared__ alignas(16) ushortt sA[128*136];
  __shared__ int sEf[128];
  __shared__ float spb[128];
  __shared__ float wagg[4][128];
  if (tid < 128){ sEf[tid] = ef[(b*NN + tid)*NN + j]; spb[tid] = bg[tid]; }
  __syncthreads();
  for (int idx = tid; idx < 4096; idx += 256){
    int i = idx >> 5, c = idx & 31;
    float4 xv = ((const float4*)xfin)[(b*NN + i)*32 + c];
    float4 bv = ((const float4*)bemb)[sEf[i]*32 + c];
    ushort4 o;
    o.x = f2us(xv.x + bv.x); o.y = f2us(xv.y + bv.y);
    o.z = f2us(xv.z + bv.z); o.w = f2us(xv.w + bv.w);
    *(ushort4*)&sA[i*136 + c*4] = o;
  }
  __syncthreads();
  f32x4 acc[2][8];
  #pragma unroll
  for (int mt=0;mt<2;mt++)
    #pragma unroll
    for (int nt=0;nt<8;nt++) acc[mt][nt] = (f32x4){0.f,0.f,0.f,0.f};
  #pragma unroll
  for (int kk = 0; kk < 128; kk += 32){
    bf16x8 af[2], bfr[8];
    #pragma unroll
    for (int mt=0;mt<2;mt++) af[mt] = *(const bf16x8*)&sA[(w*32+mt*16+l15)*136 + kk + quad*8];
    #pragma unroll
    for (int nt=0;nt<8;nt++) bfr[nt] = *(const bf16x8*)&wbf[(nt*16+l15)*128 + kk + quad*8];
    #pragma unroll
    for (int mt=0;mt<2;mt++)
      #pragma unroll
      for (int nt=0;nt<8;nt++)
        acc[mt][nt] = __builtin_amdgcn_mfma_f32_16x16x32_bf16(af[mt], bfr[nt], acc[mt][nt], 0, 0, 0);
  }
  float hsum[8];
  #pragma unroll
  for (int nt=0;nt<8;nt++) hsum[nt] = 0.f;
  #pragma unroll
  for (int mt=0;mt<2;mt++)
    #pragma unroll
    for (int nt=0;nt<8;nt++){
      int h = nt*16 + l15;
      float pb = spb[h];
      float ts = 0.f;
      #pragma unroll
      for (int reg=0;reg<4;reg++){
        int i = w*32 + mt*16 + quad*4 + reg;
        float bs = b2f(bases[(((size_t)b*NN + i)*NN + j)*HH + h]);
        float v = gelu_f(acc[mt][nt][reg] + pb) * bs;
        ts += (i < len) ? v : 0.f;
      }
      hsum[nt] += ts;
    }
  #pragma unroll
  for (int nt=0;nt<8;nt++){
    float hs = hsum[nt];
    hs += __shfl_down(hs, 32);
    hs += __shfl_down(hs, 16);
    if (lane < 16) wagg[w][nt*16 + lane] = hs;
  }
  __syncthreads();
  if (tid < 128){
    float agg = wagg[0][tid] + wagg[1][tid] + wagg[2][tid] + wagg[3][tid];
    int o = (b*NN + j)*HH + tid;
    xfout[o] = xfin[o] + agg;
  }
}

__global__ void k_g1(const float* __restrict__ xf, const float* w, const float* bias,
                     float* __restrict__ t1){
  int row=blockIdx.x, tid=threadIdx.x;
  __shared__ float xr[128];
  xr[tid]=xf[row*HH+tid]; __syncthreads();
  const float* wr = w + tid*HH;
  float acc=bias[tid];
  for (int m=0;m<HH;m++) acc+=xr[m]*wr[m];
  t1[row*HH+tid]=acc;
}

__global__ void k_bnstats(const float* __restrict__ t, const int* __restrict__ length,
                          float* __restrict__ meano, float* __restrict__ istdo){
  int f = blockIdx.x, tid = threadIdx.x;
  __shared__ float s1[256], s2[256];
  float a=0.f, a2=0.f;
  for (int r=tid;r<BB*NN;r+=256){ int b=r>>7, n=r&127;
    if (n < length[b]){ float x = t[r*HH+f]; a+=x; a2+=x*x; } }
  s1[tid]=a; s2[tid]=a2; __syncthreads();
  for (int st=128;st>0;st>>=1){ if(tid<st){ s1[tid]+=s1[tid+st]; s2[tid]+=s2[tid+st]; } __syncthreads(); }
  if (tid==0){
    float cnt=0.f; for (int b=0;b<BB;b++) cnt += (float)length[b];
    float mu = s1[0]/cnt; float var = s2[0]/cnt - mu*mu;
    meano[f]=mu; istdo[f]=rsqrtf(fmaxf(var,0.0f)+EPSV);
  }
}

__global__ void k_g2(const float* __restrict__ t1, const float* mean1, const float* istd1,
                     const float* g1, const float* bb1, const float* w2, const float* bias2,
                     float* __restrict__ t2){
  int row=blockIdx.x, tid=threadIdx.x;
  __shared__ float yr[128];
  float x = t1[row*HH+tid];
  float y = (x-mean1[tid])*istd1[tid]*g1[tid]+bb1[tid];
  yr[tid] = fmaxf(y,0.0f); __syncthreads();
  const float* wr = w2 + tid*HH;
  float acc=bias2[tid];
  for (int m=0;m<HH;m++) acc+=yr[m]*wr[m];
  t2[row*HH+tid]=acc;
}

__global__ void k_apply(const float* __restrict__ t2, const float* mean2, const float* istd2,
                        const float* g2, const float* bb2, float* __restrict__ xf){
  int idx = blockIdx.x*256+threadIdx.x;
  int f = idx & 127;
  float x = t2[idx];
  float y = (x-mean2[f])*istd2[f]*g2[f]+bb2[f];
  xf[idx] += fmaxf(y,0.0f);
}

__global__ void k_pool(const float* __restrict__ xf, const int* __restrict__ length,
                       const float* lw, const float* lb, float* __restrict__ outp){
  int b = blockIdx.x, tid=threadIdx.x;
  int len = length[b];
  float s=0.f;
  for (int n2=0;n2<len;n2++) s += xf[(b*NN+n2)*HH+tid];
  s /= (float)len;
  __shared__ float red[128];
  red[tid]=s*lw[tid]; __syncthreads();
  for (int st=64;st>0;st>>=1){ if(tid<st) red[tid]+=red[tid+st]; __syncthreads(); }
  if (tid==0) outp[b]=red[0]+lb[0];
}

// ---------------- host ----------------

extern "C" void kernel_launch(void* const* d_in, const int* in_sizes, int n_in,
                              void* d_out, int out_size, void* d_ws, size_t ws_size,
                              hipStream_t stream) {
  (void)in_sizes; (void)n_in; (void)out_size; (void)ws_size;
  const float* e        = (const float*)d_in[0];
  const float* u        = (const float*)d_in[1];
  const float* atom_emb = (const float*)d_in[2];
  const float* bond_emb = (const float*)d_in[3];
  const float* eigw_W   = (const float*)d_in[4];
  const float* eigw_b   = (const float*)d_in[5];
  const float* mng      = (const float*)d_in[6];
  const float* mnb      = (const float*)d_in[7];
  const float* qkvW     = (const float*)d_in[8];
  const float* qkvb     = (const float*)d_in[9];
  const float* outW     = (const float*)d_in[10];
  const float* outb     = (const float*)d_in[11];
  const float* fng      = (const float*)d_in[12];
  const float* fnb      = (const float*)d_in[13];
  const float* ffn1W    = (const float*)d_in[14];
  const float* ffn1b    = (const float*)d_in[15];
  const float* ffn2W    = (const float*)d_in[16];
  const float* ffn2b    = (const float*)d_in[17];
  const float* decW     = (const float*)d_in[18];
  const float* decb     = (const float*)d_in[19];
  const float* fe1W     = (const float*)d_in[20];
  const float* fe1b     = (const float*)d_in[21];
  const float* fe2W     = (const float*)d_in[22];
  const float* fe2b     = (const float*)d_in[23];
  const float* preW     = (const float*)d_in[24];
  const float* preb     = (const float*)d_in[25];
  const float* f1W      = (const float*)d_in[26];
  const float* f1b      = (const float*)d_in[27];
  const float* bn1g     = (const float*)d_in[28];
  const float* bn1b     = (const float*)d_in[29];
  const float* f2W      = (const float*)d_in[30];
  const float* f2b      = (const float*)d_in[31];
  const float* bn2g     = (const float*)d_in[32];
  const float* bn2b     = (const float*)d_in[33];
  const float* linW     = (const float*)d_in[34];
  const float* linb     = (const float*)d_in[35];
  const int* nodef      = (const int*)d_in[36];
  const int* edgef      = (const int*)d_in[37];
  const int* length     = (const int*)d_in[38];

  float* outp = (float*)d_out;   // h[8] ++ new_e[4096] ++ attn[524288], f32

  char* p = (char*)d_ws;
  auto alloc = [&](size_t bytes)->void*{ void* r=(void*)p; p += (bytes+255)&~(size_t)255; return r; };
  const int TOK = BB*NN*HH;           // 131072
  float* eig   = (float*)alloc(TOK*4);
  float* q     = (float*)alloc(TOK*4);
  float* k     = (float*)alloc(TOK*4);
  float* v     = (float*)alloc(TOK*4);
  float* attnf = (float*)alloc((size_t)BB*NHD*NN*NN*4);
  float* ctx   = (float*)alloc(TOK*4);
  float* newe  = (float*)alloc(BB*NHD*NN*4);
  float* filt  = (float*)alloc((size_t)BB*NN*NN*4*4);
  bf16*  bases = (bf16*) alloc((size_t)BB*NN*NN*HH*2);
  float* xf0   = (float*)alloc(TOK*4);
  float* xf1   = (float*)alloc(TOK*4);
  float* t1    = (float*)alloc(TOK*4);
  float* t2    = (float*)alloc(TOK*4);
  float* mean1 = (float*)alloc(128*4);
  float* istd1 = (float*)alloc(128*4);
  float* mean2 = (float*)alloc(128*4);
  float* istd2 = (float*)alloc(128*4);
  ushortt* wbf = (ushortt*)alloc(81920*2);   // fe2W bf16 + preW[4] bf16

  k_cvtw<<<320, 256, 0, stream>>>(fe2W, preW, wbf);

  // front end
  k_sine_eig<<<BB*NN, 128, 0, stream>>>(e, eigw_W, eigw_b, eig);
  k_ln_qkv<<<BB*NN, 128, 0, stream>>>(eig, mng, mnb, qkvW, qkvb, q, k, v);
  k_attn<<<BB*NHD*NN, 128, 0, stream>>>(q, k, length, attnf, outp);
  k_ctx<<<BB*NN, 128, 0, stream>>>(attnf, v, ctx);
  k_outproj<<<BB*NN, 128, 0, stream>>>(ctx, outW, outb, eig);
  k_ffn<<<BB*NN, 128, 0, stream>>>(eig, fng, fnb, ffn1W, ffn1b, ffn2W, ffn2b);
  k_dec<<<BB, 128, 0, stream>>>(eig, decW, decb, newe, outp);

  // bases
  k_filters<<<dim3(BB,8,8), dim3(16,16), 0, stream>>>(u, newe, filt);
  k_fe2<<<BB*NN, 256, 0, stream>>>(filt, fe1W, fe1b, wbf, fe2b, bases);

  // message passing
  k_xfinit<<<TOK/256, 256, 0, stream>>>(atom_emb, nodef, xf0);
  float* src = xf0; float* dst = xf1;
  for (int l=0;l<LAY;l++){
    k_pre2<<<BB*NN, 256, 0, stream>>>(src, dst, bases, bond_emb, edgef, length,
                                      wbf + 16384 + l*16384, preb + l*HH);
    k_g1<<<BB*NN, 128, 0, stream>>>(dst, f1W + (size_t)l*HH*HH, f1b + l*HH, t1);
    k_bnstats<<<128, 256, 0, stream>>>(t1, length, mean1, istd1);
    k_g2<<<BB*NN, 128, 0, stream>>>(t1, mean1, istd1, bn1g + l*HH, bn1b + l*HH,
                                    f2W + (size_t)l*HH*HH, f2b + l*HH, t2);
    k_bnstats<<<128, 256, 0, stream>>>(t2, length, mean2, istd2);
    k_apply<<<TOK/256, 256, 0, stream>>>(t2, mean2, istd2, bn2g + l*HH, bn2b + l*HH, dst);
    float* tmp = src; src = dst; dst = tmp;
  }
  // after loop final xf is in src (xf0)
  k_pool<<<BB, 128, 0, stream>>>(src, length, linW, linb, outp);
}

// Round 6
// 570.583 us; speedup vs baseline: 3.8967x; 1.1357x over previous
//
#include <hip/hip_runtime.h>
#include <hip/hip_bf16.h>
#include <math.h>

#define BB 8
#define NN 128
#define HH 128
#define NHD 4
#define DHD 32
#define LAY 4
#define EPSV 1e-5f

typedef __hip_bfloat16 bf16;
typedef unsigned short ushortt;
typedef short bf16x8 __attribute__((ext_vector_type(8)));
typedef float f32x4 __attribute__((ext_vector_type(4)));

__device__ __forceinline__ float b2f(bf16 x){ return __bfloat162float(x); }
__device__ __forceinline__ bf16 f2b(float x){ return __float2bfloat16(x); }
__device__ __forceinline__ float us2f(ushortt u){ return __uint_as_float(((unsigned)u)<<16); }
__device__ __forceinline__ ushortt f2us(float x){ bf16 b=__float2bfloat16(x); return *(ushortt*)&b; }
__device__ __forceinline__ float gelu_f(float x){ return 0.5f*x*(1.0f+erff(x*0.7071067811865476f)); }

// ---------------- front end (all f32 — precision-critical for new_e) ----------------

// fused sine-encoding + eig linear + LN + QKV
__global__ void k_fe_a(const float* __restrict__ e, const float* __restrict__ eigW,
                       const float* __restrict__ eigb, const float* __restrict__ g,
                       const float* __restrict__ bt, const float* __restrict__ qkvW,
                       const float* __restrict__ qkvb,
                       float* __restrict__ eigout, float* __restrict__ q,
                       float* __restrict__ k, float* __restrict__ v){
  int row = blockIdx.x; int tid = threadIdx.x;
  __shared__ float ee[129]; __shared__ float buf[128]; __shared__ float xm[128];
  float ev = e[row];
  if (tid < 64){
    float dv = expf(-0.1439115683121279f * (float)tid);
    float pe = ev * 100.0f * dv;
    ee[1+tid] = sinf(pe);
    ee[65+tid] = cosf(pe);
  }
  if (tid == 0) ee[0] = ev;
  __syncthreads();
  const float* wr = eigW + tid*129;
  float x = eigb[tid];
  for (int k2=0;k2<129;k2++) x += ee[k2]*wr[k2];
  eigout[row*HH+tid] = x;
  // LayerNorm
  buf[tid]=x; __syncthreads();
  for (int s2=64;s2>0;s2>>=1){ if(tid<s2) buf[tid]+=buf[tid+s2]; __syncthreads(); }
  float mean = buf[0]*(1.0f/128.0f); __syncthreads();
  float d = x-mean; buf[tid]=d*d; __syncthreads();
  for (int s2=64;s2>0;s2>>=1){ if(tid<s2) buf[tid]+=buf[tid+s2]; __syncthreads(); }
  float var = buf[0]*(1.0f/128.0f);
  xm[tid] = d*rsqrtf(var+EPSV)*g[tid]+bt[tid];
  __syncthreads();
  float* outs[3] = {q,k,v};
  for (int s3=0;s3<3;s3++){
    const float* wq = qkvW + (s3*HH+tid)*HH;
    float acc = qkvb[s3*HH+tid];
    for (int m=0;m<HH;m++) acc += xm[m]*wq[m];
    outs[s3][row*HH+tid]=acc;
  }
}

__global__ void k_attn(const float* __restrict__ q, const float* __restrict__ k,
                       const int* __restrict__ length,
                       float* __restrict__ attnf, float* __restrict__ outp){
  int bx = blockIdx.x;
  int qi = bx & 127, hd = (bx>>7)&3, b = bx>>9;
  int tid = threadIdx.x;
  int len = length[b];
  __shared__ float qv[DHD]; __shared__ float red[128];
  if (tid < DHD) qv[tid] = q[(b*NN+qi)*HH + hd*DHD + tid];
  __syncthreads();
  float s = -1e30f;
  if (tid < len){
    const float* kr = k + (b*NN+tid)*HH + hd*DHD;
    float sc=0.f;
    for (int d2=0; d2<DHD; d2++) sc += qv[d2]*kr[d2];
    s = sc * 0.17677669529663687f; // 1/sqrt(32)
  }
  red[tid]=s; __syncthreads();
  for (int st=64;st>0;st>>=1){ if(tid<st) red[tid]=fmaxf(red[tid],red[tid+st]); __syncthreads(); }
  float mx = red[0]; __syncthreads();
  float p = (tid<len)? expf(s-mx):0.0f;
  red[tid]=p; __syncthreads();
  for (int st=64;st>0;st>>=1){ if(tid<st) red[tid]+=red[tid+st]; __syncthreads(); }
  float a = p / red[0];
  int idx = ((b*NHD+hd)*NN+qi)*NN+tid;
  attnf[idx]=a;
  outp[4104 + idx]=a;   // attn at element offset 8+4096
}

// fused ctx + out-proj + FFN (residual chain kept block-local)
__global__ void k_fe_c(const float* __restrict__ attnf, const float* __restrict__ v,
                       const float* __restrict__ outW, const float* __restrict__ outb,
                       const float* __restrict__ fng, const float* __restrict__ fnb,
                       const float* __restrict__ w1, const float* __restrict__ b1,
                       const float* __restrict__ w2, const float* __restrict__ b2,
                       float* __restrict__ eig){
  int row = blockIdx.x; int b = row>>7, qi = row&127;
  int tid = threadIdx.x;
  __shared__ float c[128]; __shared__ float buf[128]; __shared__ float xm[128]; __shared__ float tt[128];
  int hd = tid>>5;
  const float* ar = attnf + ((b*NHD+hd)*NN+qi)*NN;
  float acc=0.f;
  for (int j=0;j<NN;j++) acc += ar[j]*v[(b*NN+j)*HH+tid];
  c[tid]=acc; __syncthreads();
  const float* wro = outW + tid*HH;
  float o = outb[tid];
  for (int m=0;m<HH;m++) o += c[m]*wro[m];
  float x = eig[row*HH+tid] + o;
  // LN
  buf[tid]=x; __syncthreads();
  for (int s2=64;s2>0;s2>>=1){ if(tid<s2) buf[tid]+=buf[tid+s2]; __syncthreads(); }
  float mean=buf[0]*(1.f/128.f); __syncthreads();
  float d=x-mean; buf[tid]=d*d; __syncthreads();
  for (int s2=64;s2>0;s2>>=1){ if(tid<s2) buf[tid]+=buf[tid+s2]; __syncthreads(); }
  float var=buf[0]*(1.f/128.f);
  xm[tid]=d*rsqrtf(var+EPSV)*fng[tid]+fnb[tid];
  __syncthreads();
  const float* wr1=w1+tid*HH;
  float a1=b1[tid];
  for (int m=0;m<HH;m++) a1+=xm[m]*wr1[m];
  tt[tid]=gelu_f(a1); __syncthreads();
  const float* wr2=w2+tid*HH;
  float a2=b2[tid];
  for (int m=0;m<HH;m++) a2+=tt[m]*wr2[m];
  eig[row*HH+tid]=x+a2;
}

__global__ void k_dec(const float* __restrict__ eig, const float* dW, const float* db,
                      float* __restrict__ newe, float* __restrict__ outp){
  int b = blockIdx.x, n = threadIdx.x;
  __shared__ float w[NHD*HH];
  for (int i=n;i<NHD*HH;i+=128) w[i]=dW[i];
  __syncthreads();
  float acc[NHD];
  #pragma unroll
  for (int kk=0;kk<NHD;kk++) acc[kk]=db[kk];
  const float* er = eig + (b*NN+n)*HH;
  for (int h2=0;h2<HH;h2++){
    float ev = er[h2];
    #pragma unroll
    for (int kk=0;kk<NHD;kk++) acc[kk]+=ev*w[kk*HH+h2];
  }
  #pragma unroll
  for (int kk=0;kk<NHD;kk++){
    int idx=(b*NHD+kk)*NN+n; newe[idx]=acc[kk];
    outp[8 + idx]=acc[kk];  // new_e at element offset 8
  }
}

// ---------------- bases ----------------

__global__ void k_filters(const float* __restrict__ u, const float* __restrict__ newe,
                          float* __restrict__ filt){
  int b = blockIdx.x, n0 = blockIdx.y*16, p0 = blockIdx.z*16;
  int tx = threadIdx.x, ty = threadIdx.y; int tid = ty*16+tx;
  __shared__ float un[16][17], upt[16][17], wk[4][16];
  float acc[4]={0.f,0.f,0.f,0.f};
  for (int mt=0; mt<8; mt++){
    __syncthreads();
    un[ty][tx]  = u[(b*NN+n0+ty)*NN + mt*16+tx];
    upt[tx][ty] = u[(b*NN+p0+ty)*NN + mt*16+tx];
    if (tid<64) wk[tid>>4][tid&15] = newe[(b*NHD+(tid>>4))*NN + mt*16 + (tid&15)];
    __syncthreads();
    #pragma unroll
    for (int mm=0;mm<16;mm++){
      float pr = un[ty][mm]*upt[mm][tx];
      #pragma unroll
      for (int kk=0;kk<4;kk++) acc[kk] += pr*wk[kk][mm];
    }
  }
  float4 o; o.x=acc[0];o.y=acc[1];o.z=acc[2];o.w=acc[3];
  *(float4*)&filt[((b*NN+n0+ty)*NN+p0+tx)*4] = o;
}

// convert fe2W (16384) + preW (4*16384) to bf16 once; also zero stats accumulators
__global__ void k_cvtw(const float* __restrict__ fe2W, const float* __restrict__ preW,
                       ushortt* __restrict__ wbf, float* __restrict__ gs){
  int idx = blockIdx.x*256 + threadIdx.x;
  if (idx < 2048) gs[idx] = 0.f;
  if (idx >= 81920) return;
  float v = (idx < 16384) ? fe2W[idx] : preW[idx - 16384];
  wbf[idx] = f2us(v);
}

// bases = gelu(gelu(in5@fe1W^T+b1)@fe2W^T+b2); A-fragments computed in registers (no LDS A)
__global__ __launch_bounds__(256) void k_fe2(const float* __restrict__ filt,
    const float* __restrict__ w1g, const float* __restrict__ b1g,
    const ushortt* __restrict__ w2bf, const float* __restrict__ b2g,
    bf16* __restrict__ bases){
  int bi = blockIdx.x;            // b*128 + n
  int nloc = bi & 127;
  int tid = threadIdx.x;
  int lane = tid & 63, w = tid >> 6, quad = lane >> 4, l15 = lane & 15;
  __shared__ float4 sF[128];
  __shared__ float w1[640], b1s[128], b2s[128];
  if (tid < 128) sF[tid] = ((const float4*)filt)[bi*128 + tid];
  for (int i = tid; i < 640; i += 256) w1[i] = w1g[i];
  if (tid < 128){ b1s[tid] = b1g[tid]; b2s[tid] = b2g[tid]; }
  __syncthreads();
  float4 f4[2]; float dg[2];
  #pragma unroll
  for (int mt=0;mt<2;mt++){
    int r = w*32 + mt*16 + l15;
    f4[mt] = sF[r];
    dg[mt] = (r == nloc) ? 1.0f : 0.0f;
  }
  f32x4 acc[2][8];
  #pragma unroll
  for (int mt=0;mt<2;mt++)
    #pragma unroll
    for (int nt=0;nt<8;nt++) acc[mt][nt] = (f32x4){0.f,0.f,0.f,0.f};
  for (int kk = 0; kk < 128; kk += 32){
    bf16x8 af[2];
    #pragma unroll
    for (int mt=0;mt<2;mt++){
      #pragma unroll
      for (int j=0;j<8;j++){
        int m = kk + quad*8 + j;
        float a = b1s[m] + w1[m*5]*dg[mt] + w1[m*5+1]*f4[mt].x + w1[m*5+2]*f4[mt].y
                + w1[m*5+3]*f4[mt].z + w1[m*5+4]*f4[mt].w;
        af[mt][j] = (short)f2us(gelu_f(a));
      }
    }
    bf16x8 bfr[8];
    #pragma unroll
    for (int nt=0;nt<8;nt++) bfr[nt] = *(const bf16x8*)&w2bf[(nt*16+l15)*128 + kk + quad*8];
    #pragma unroll
    for (int mt=0;mt<2;mt++)
      #pragma unroll
      for (int nt=0;nt<8;nt++)
        acc[mt][nt] = __builtin_amdgcn_mfma_f32_16x16x32_bf16(af[mt], bfr[nt], acc[mt][nt], 0, 0, 0);
  }
  #pragma unroll
  for (int mt=0;mt<2;mt++)
    #pragma unroll
    for (int nt=0;nt<8;nt++){
      int h = nt*16 + l15;
      float bb = b2s[h];
      #pragma unroll
      for (int reg=0;reg<4;reg++){
        int pr = w*32 + mt*16 + quad*4 + reg;
        bases[((size_t)bi*128 + pr)*128 + h] = f2b(gelu_f(acc[mt][nt][reg] + bb));
      }
    }
}

// ---------------- message passing ----------------

__global__ void k_xfinit(const float* __restrict__ aemb, const int* __restrict__ nf,
                         float* __restrict__ xf){
  int idx = blockIdx.x*256+threadIdx.x;
  int node = idx >> 7, h2 = idx & 127;
  xf[idx] = aemb[nf[node]*HH + h2];
}

// per-layer: xfW = xf @ preW^T (MFMA, blocks 0..7); bondW[e] = bond_emb[e]@preW^T + preb (block 8)
__global__ __launch_bounds__(256) void k_xwl(const float* __restrict__ xf,
    const ushortt* __restrict__ wbfl, const float* __restrict__ bemb,
    const float* __restrict__ pb, float* __restrict__ xfW, float* __restrict__ bondW){
  int blk = blockIdx.x;
  int tid = threadIdx.x;
  if (blk == 8){
    for (int idx = tid; idx < 1280; idx += 256){
      int e2 = idx >> 7, h = idx & 127;
      const float* br = bemb + e2*128;
      const ushortt* wr = wbfl + h*128;
      float acc = pb[h];
      for (int m=0;m<128;m++) acc += br[m]*us2f(wr[m]);
      bondW[idx] = acc;
    }
    return;
  }
  int lane = tid & 63, w = tid >> 6, quad = lane >> 4, l15 = lane & 15;
  __shared__ alignas(16) ushortt sA[128*136];
  for (int idx = tid; idx < 4096; idx += 256){
    int r = idx >> 5, c = idx & 31;
    float4 xv = ((const float4*)xf)[(blk*128 + r)*32 + c];
    ushort4 o;
    o.x=f2us(xv.x); o.y=f2us(xv.y); o.z=f2us(xv.z); o.w=f2us(xv.w);
    *(ushort4*)&sA[r*136 + c*4] = o;
  }
  __syncthreads();
  f32x4 acc[2][8];
  #pragma unroll
  for (int mt=0;mt<2;mt++)
    #pragma unroll
    for (int nt=0;nt<8;nt++) acc[mt][nt] = (f32x4){0.f,0.f,0.f,0.f};
  #pragma unroll
  for (int kk = 0; kk < 128; kk += 32){
    bf16x8 af[2], bfr[8];
    #pragma unroll
    for (int mt=0;mt<2;mt++) af[mt] = *(const bf16x8*)&sA[(w*32+mt*16+l15)*136 + kk + quad*8];
    #pragma unroll
    for (int nt=0;nt<8;nt++) bfr[nt] = *(const bf16x8*)&wbfl[(nt*16+l15)*128 + kk + quad*8];
    #pragma unroll
    for (int mt=0;mt<2;mt++)
      #pragma unroll
      for (int nt=0;nt<8;nt++)
        acc[mt][nt] = __builtin_amdgcn_mfma_f32_16x16x32_bf16(af[mt], bfr[nt], acc[mt][nt], 0, 0, 0);
  }
  #pragma unroll
  for (int mt=0;mt<2;mt++)
    #pragma unroll
    for (int nt=0;nt<8;nt++){
      int h = nt*16 + l15;
      #pragma unroll
      for (int reg=0;reg<4;reg++){
        int pr = w*32 + mt*16 + quad*4 + reg;
        xfW[(blk*128 + pr)*128 + h] = acc[mt][nt][reg];
      }
    }
}

// per-edge elementwise: aggr[j,h] = sum_i gelu(xfW[i,h]+bondW[ef[i,j],h]) * bases[i,j,h]
__global__ __launch_bounds__(256) void k_edge(const float* __restrict__ xfin, float* __restrict__ xfout,
    const bf16* __restrict__ bases, const float* __restrict__ xfW,
    const float* __restrict__ bondW, const int* __restrict__ ef,
    const int* __restrict__ length){
  int bj = blockIdx.x; int b = bj >> 7, j = bj & 127;
  int len = length[b];
  int tid = threadIdx.x; int h = tid & 127, ih = tid >> 7;
  __shared__ float sBW[10][128];
  __shared__ int sEf[128];
  __shared__ float part[2][128];
  for (int idx = tid; idx < 1280; idx += 256) sBW[idx>>7][idx&127] = bondW[idx];
  if (tid < 128) sEf[tid] = ef[(b*NN + tid)*NN + j];
  __syncthreads();
  float agg = 0.f;
  if (j < len){
    const float* xwb = xfW + b*NN*HH + h;
    const bf16* bb = bases + (size_t)b*NN*NN*HH + (size_t)j*HH + h;
    for (int i = ih; i < len; i += 2){
      float vv = gelu_f(xwb[i*128] + sBW[sEf[i]][h]);
      agg += vv * b2f(bb[(size_t)i*16384]);
    }
  }
  part[ih][h] = agg; __syncthreads();
  if (tid < 128){
    int o = (b*NN + j)*HH + tid;
    xfout[o] = xfin[o] + part[0][tid] + part[1][tid];
  }
}

// g1 GEMM + masked partial BN stats (8 rows/block)
__global__ __launch_bounds__(256) void k_g1s(const float* __restrict__ xf,
    const float* __restrict__ w, const float* __restrict__ bias,
    const int* __restrict__ length, float* __restrict__ t1,
    float* __restrict__ gsum, float* __restrict__ gsq){
  int blk = blockIdx.x; int tid = threadIdx.x;
  int f = tid & 127, rh = tid >> 7;
  __shared__ float sx[8][128];
  __shared__ float red1[2][128], red2[2][128];
  int r0 = blk*8;
  for (int idx = tid; idx < 1024; idx += 256){
    int r = idx >> 7, m = idx & 127;
    sx[r][m] = xf[(r0+r)*128 + m];
  }
  __syncthreads();
  const float* wr = w + f*128;
  float bsv = bias[f];
  float s=0.f, s2=0.f;
  for (int rr = rh*4; rr < rh*4+4; rr++){
    int rg = r0 + rr; int b = rg >> 7, n = rg & 127;
    float acc = bsv;
    for (int m=0;m<128;m++) acc += sx[rr][m]*wr[m];
    t1[rg*128+f] = acc;
    if (n < length[b]){ s += acc; s2 += acc*acc; }
  }
  red1[rh][f]=s; red2[rh][f]=s2; __syncthreads();
  if (tid < 128){
    atomicAdd(&gsum[tid], red1[0][tid]+red1[1][tid]);
    atomicAdd(&gsq[tid],  red2[0][tid]+red2[1][tid]);
  }
}

// finalize BN1 + relu + g2 GEMM + partial BN2 stats
__global__ __launch_bounds__(256) void k_g2s(const float* __restrict__ t1,
    const float* __restrict__ gsum1, const float* __restrict__ gsq1,
    const float* __restrict__ g1, const float* __restrict__ bb1,
    const float* __restrict__ w2, const float* __restrict__ bias2,
    const int* __restrict__ length, float* __restrict__ t2,
    float* __restrict__ gsum2, float* __restrict__ gsq2){
  int blk = blockIdx.x; int tid = threadIdx.x;
  int f = tid & 127, rh = tid >> 7;
  __shared__ float sy[8][128];
  __shared__ float red1[2][128], red2[2][128];
  int r0 = blk*8;
  float cnt = 0.f;
  for (int b=0;b<BB;b++) cnt += (float)length[b];
  float mu = gsum1[f]/cnt;
  float var = gsq1[f]/cnt - mu*mu;
  float istd = rsqrtf(fmaxf(var,0.0f)+EPSV);
  float gg = g1[f], bbv = bb1[f];
  for (int idx = tid; idx < 1024; idx += 256){
    int r = idx >> 7;            // m == f for this thread (stride 256 keeps low 7 bits)
    float x = t1[(r0+r)*128 + f];
    float y = (x-mu)*istd*gg + bbv;
    sy[r][f] = fmaxf(y, 0.0f);
  }
  __syncthreads();
  const float* wr = w2 + f*128;
  float bsv = bias2[f];
  float s=0.f, s2=0.f;
  for (int rr = rh*4; rr < rh*4+4; rr++){
    int rg = r0 + rr; int b = rg >> 7, n = rg & 127;
    float acc = bsv;
    for (int m=0;m<128;m++) acc += sy[rr][m]*wr[m];
    t2[rg*128+f] = acc;
    if (n < length[b]){ s += acc; s2 += acc*acc; }
  }
  red1[rh][f]=s; red2[rh][f]=s2; __syncthreads();
  if (tid < 128){
    atomicAdd(&gsum2[tid], red1[0][tid]+red1[1][tid]);
    atomicAdd(&gsq2[tid],  red2[0][tid]+red2[1][tid]);
  }
}

// finalize BN2 + relu + residual add
__global__ void k_apply2(const float* __restrict__ t2, const float* __restrict__ gsum2,
    const float* __restrict__ gsq2, const float* __restrict__ g2,
    const float* __restrict__ bb2, const int* __restrict__ length,
    float* __restrict__ xf){
  int idx = blockIdx.x*256+threadIdx.x;
  int f = idx & 127;
  float cnt = 0.f;
  for (int b=0;b<BB;b++) cnt += (float)length[b];
  float mu = gsum2[f]/cnt;
  float var = gsq2[f]/cnt - mu*mu;
  float istd = rsqrtf(fmaxf(var,0.0f)+EPSV);
  float x = t2[idx];
  float y = (x-mu)*istd*g2[f]+bb2[f];
  xf[idx] += fmaxf(y,0.0f);
}

__global__ void k_pool(const float* __restrict__ xf, const int* __restrict__ length,
                       const float* lw, const float* lb, float* __restrict__ outp){
  int b = blockIdx.x, tid=threadIdx.x;
  int len = length[b];
  float s=0.f;
  for (int n2=0;n2<len;n2++) s += xf[(b*NN+n2)*HH+tid];
  s /= (float)len;
  __shared__ float red[128];
  red[tid]=s*lw[tid]; __syncthreads();
  for (int st=64;st>0;st>>=1){ if(tid<st) red[tid]+=red[tid+st]; __syncthreads(); }
  if (tid==0) outp[b]=red[0]+lb[0];
}

// ---------------- host ----------------

extern "C" void kernel_launch(void* const* d_in, const int* in_sizes, int n_in,
                              void* d_out, int out_size, void* d_ws, size_t ws_size,
                              hipStream_t stream) {
  (void)in_sizes; (void)n_in; (void)out_size; (void)ws_size;
  const float* e        = (const float*)d_in[0];
  const float* u        = (const float*)d_in[1];
  const float* atom_emb = (const float*)d_in[2];
  const float* bond_emb = (const float*)d_in[3];
  const float* eigw_W   = (const float*)d_in[4];
  const float* eigw_b   = (const float*)d_in[5];
  const float* mng      = (const float*)d_in[6];
  const float* mnb      = (const float*)d_in[7];
  const float* qkvW     = (const float*)d_in[8];
  const float* qkvb     = (const float*)d_in[9];
  const float* outW     = (const float*)d_in[10];
  const float* outb     = (const float*)d_in[11];
  const float* fng      = (const float*)d_in[12];
  const float* fnb      = (const float*)d_in[13];
  const float* ffn1W    = (const float*)d_in[14];
  const float* ffn1b    = (const float*)d_in[15];
  const float* ffn2W    = (const float*)d_in[16];
  const float* ffn2b    = (const float*)d_in[17];
  const float* decW     = (const float*)d_in[18];
  const float* decb     = (const float*)d_in[19];
  const float* fe1W     = (const float*)d_in[20];
  const float* fe1b     = (const float*)d_in[21];
  const float* fe2W     = (const float*)d_in[22];
  const float* fe2b     = (const float*)d_in[23];
  const float* preW     = (const float*)d_in[24];
  const float* preb     = (const float*)d_in[25];
  const float* f1W      = (const float*)d_in[26];
  const float* f1b      = (const float*)d_in[27];
  const float* bn1g     = (const float*)d_in[28];
  const float* bn1b     = (const float*)d_in[29];
  const float* f2W      = (const float*)d_in[30];
  const float* f2b      = (const float*)d_in[31];
  const float* bn2g     = (const float*)d_in[32];
  const float* bn2b     = (const float*)d_in[33];
  const float* linW     = (const float*)d_in[34];
  const float* linb     = (const float*)d_in[35];
  const int* nodef      = (const int*)d_in[36];
  const int* edgef      = (const int*)d_in[37];
  const int* length     = (const int*)d_in[38];

  float* outp = (float*)d_out;   // h[8] ++ new_e[4096] ++ attn[524288], f32

  char* p = (char*)d_ws;
  auto alloc = [&](size_t bytes)->void*{ void* r=(void*)p; p += (bytes+255)&~(size_t)255; return r; };
  const int TOK = BB*NN*HH;           // 131072
  float* eig   = (float*)alloc(TOK*4);
  float* q     = (float*)alloc(TOK*4);
  float* k     = (float*)alloc(TOK*4);
  float* v     = (float*)alloc(TOK*4);
  float* attnf = (float*)alloc((size_t)BB*NHD*NN*NN*4);
  float* newe  = (float*)alloc(BB*NHD*NN*4);
  float* filt  = (float*)alloc((size_t)BB*NN*NN*4*4);
  bf16*  bases = (bf16*) alloc((size_t)BB*NN*NN*HH*2);
  float* xf0   = (float*)alloc(TOK*4);
  float* xf1   = (float*)alloc(TOK*4);
  float* t1    = (float*)alloc(TOK*4);
  float* t2    = (float*)alloc(TOK*4);
  float* xfW   = (float*)alloc(TOK*4);
  float* bondW = (float*)alloc(10*128*4);
  float* gs    = (float*)alloc(2048*4);     // per-layer BN stat accumulators (4 layers x 512)
  ushortt* wbf = (ushortt*)alloc(81920*2);  // fe2W bf16 + preW[4] bf16

  k_cvtw<<<320, 256, 0, stream>>>(fe2W, preW, wbf, gs);

  // front end
  k_fe_a<<<BB*NN, 128, 0, stream>>>(e, eigw_W, eigw_b, mng, mnb, qkvW, qkvb, eig, q, k, v);
  k_attn<<<BB*NHD*NN, 128, 0, stream>>>(q, k, length, attnf, outp);
  k_fe_c<<<BB*NN, 128, 0, stream>>>(attnf, v, outW, outb, fng, fnb,
                                    ffn1W, ffn1b, ffn2W, ffn2b, eig);
  k_dec<<<BB, 128, 0, stream>>>(eig, decW, decb, newe, outp);

  // bases
  k_filters<<<dim3(BB,8,8), dim3(16,16), 0, stream>>>(u, newe, filt);
  k_fe2<<<BB*NN, 256, 0, stream>>>(filt, fe1W, fe1b, wbf, fe2b, bases);

  // message passing
  k_xfinit<<<TOK/256, 256, 0, stream>>>(atom_emb, nodef, xf0);
  float* src = xf0; float* dst = xf1;
  for (int l=0;l<LAY;l++){
    const ushortt* wbfl = wbf + 16384 + l*16384;
    float* gsl = gs + l*512;
    k_xwl<<<9, 256, 0, stream>>>(src, wbfl, bond_emb, preb + l*HH, xfW, bondW);
    k_edge<<<BB*NN, 256, 0, stream>>>(src, dst, bases, xfW, bondW, edgef, length);
    k_g1s<<<128, 256, 0, stream>>>(dst, f1W + (size_t)l*HH*HH, f1b + l*HH, length,
                                   t1, gsl, gsl+128);
    k_g2s<<<128, 256, 0, stream>>>(t1, gsl, gsl+128, bn1g + l*HH, bn1b + l*HH,
                                   f2W + (size_t)l*HH*HH, f2b + l*HH, length,
                                   t2, gsl+256, gsl+384);
    k_apply2<<<512, 256, 0, stream>>>(t2, gsl+256, gsl+384, bn2g + l*HH, bn2b + l*HH,
                                      length, dst);
    float* tmp = src; src = dst; dst = tmp;
  }
  // after loop final xf is in src (xf0)
  k_pool<<<BB, 128, 0, stream>>>(src, length, linW, linb, outp);
}

// Round 7
// 566.900 us; speedup vs baseline: 3.9220x; 1.0065x over previous
//
#include <hip/hip_runtime.h>
#include <hip/hip_bf16.h>
#include <math.h>

#define BB 8
#define NN 128
#define HH 128
#define NHD 4
#define DHD 32
#define LAY 4
#define EPSV 1e-5f

typedef __hip_bfloat16 bf16;
typedef unsigned short ushortt;
typedef short bf16x8 __attribute__((ext_vector_type(8)));
typedef float f32x4 __attribute__((ext_vector_type(4)));

__device__ __forceinline__ float b2f(bf16 x){ return __bfloat162float(x); }
__device__ __forceinline__ bf16 f2b(float x){ return __float2bfloat16(x); }
__device__ __forceinline__ float us2f(ushortt u){ return __uint_as_float(((unsigned)u)<<16); }
__device__ __forceinline__ ushortt f2us(float x){ bf16 b=__float2bfloat16(x); return *(ushortt*)&b; }
__device__ __forceinline__ float gelu_f(float x){ return 0.5f*x*(1.0f+erff(x*0.7071067811865476f)); }

// ---------------- front end (all f32 — precision-critical for new_e) ----------------

// fused sine-encoding + eig linear + LN + QKV
__global__ void k_fe_a(const float* __restrict__ e, const float* __restrict__ eigW,
                       const float* __restrict__ eigb, const float* __restrict__ g,
                       const float* __restrict__ bt, const float* __restrict__ qkvW,
                       const float* __restrict__ qkvb,
                       float* __restrict__ eigout, float* __restrict__ q,
                       float* __restrict__ k, float* __restrict__ v){
  int row = blockIdx.x; int tid = threadIdx.x;
  __shared__ float ee[129]; __shared__ float buf[128]; __shared__ float xm[128];
  float ev = e[row];
  if (tid < 64){
    float dv = expf(-0.1439115683121279f * (float)tid);
    float pe = ev * 100.0f * dv;
    ee[1+tid] = sinf(pe);
    ee[65+tid] = cosf(pe);
  }
  if (tid == 0) ee[0] = ev;
  __syncthreads();
  const float* wr = eigW + tid*129;
  float x = eigb[tid];
  for (int k2=0;k2<129;k2++) x += ee[k2]*wr[k2];
  eigout[row*HH+tid] = x;
  // LayerNorm
  buf[tid]=x; __syncthreads();
  for (int s2=64;s2>0;s2>>=1){ if(tid<s2) buf[tid]+=buf[tid+s2]; __syncthreads(); }
  float mean = buf[0]*(1.0f/128.0f); __syncthreads();
  float d = x-mean; buf[tid]=d*d; __syncthreads();
  for (int s2=64;s2>0;s2>>=1){ if(tid<s2) buf[tid]+=buf[tid+s2]; __syncthreads(); }
  float var = buf[0]*(1.0f/128.0f);
  xm[tid] = d*rsqrtf(var+EPSV)*g[tid]+bt[tid];
  __syncthreads();
  float* outs[3] = {q,k,v};
  for (int s3=0;s3<3;s3++){
    const float* wq = qkvW + (s3*HH+tid)*HH;
    float acc = qkvb[s3*HH+tid];
    for (int m=0;m<HH;m++) acc += xm[m]*wq[m];
    outs[s3][row*HH+tid]=acc;
  }
}

__global__ void k_attn(const float* __restrict__ q, const float* __restrict__ k,
                       const int* __restrict__ length,
                       float* __restrict__ attnf, float* __restrict__ outp){
  int bx = blockIdx.x;
  int qi = bx & 127, hd = (bx>>7)&3, b = bx>>9;
  int tid = threadIdx.x;
  int len = length[b];
  __shared__ float qv[DHD]; __shared__ float red[128];
  if (tid < DHD) qv[tid] = q[(b*NN+qi)*HH + hd*DHD + tid];
  __syncthreads();
  float s = -1e30f;
  if (tid < len){
    const float* kr = k + (b*NN+tid)*HH + hd*DHD;
    float sc=0.f;
    for (int d2=0; d2<DHD; d2++) sc += qv[d2]*kr[d2];
    s = sc * 0.17677669529663687f; // 1/sqrt(32)
  }
  red[tid]=s; __syncthreads();
  for (int st=64;st>0;st>>=1){ if(tid<st) red[tid]=fmaxf(red[tid],red[tid+st]); __syncthreads(); }
  float mx = red[0]; __syncthreads();
  float p = (tid<len)? expf(s-mx):0.0f;
  red[tid]=p; __syncthreads();
  for (int st=64;st>0;st>>=1){ if(tid<st) red[tid]+=red[tid+st]; __syncthreads(); }
  float a = p / red[0];
  int idx = ((b*NHD+hd)*NN+qi)*NN+tid;
  attnf[idx]=a;
  outp[4104 + idx]=a;   // attn at element offset 8+4096
}

// fused ctx + out-proj + FFN (residual chain kept block-local)
__global__ void k_fe_c(const float* __restrict__ attnf, const float* __restrict__ v,
                       const float* __restrict__ outW, const float* __restrict__ outb,
                       const float* __restrict__ fng, const float* __restrict__ fnb,
                       const float* __restrict__ w1, const float* __restrict__ b1,
                       const float* __restrict__ w2, const float* __restrict__ b2,
                       float* __restrict__ eig){
  int row = blockIdx.x; int b = row>>7, qi = row&127;
  int tid = threadIdx.x;
  __shared__ float c[128]; __shared__ float buf[128]; __shared__ float xm[128]; __shared__ float tt[128];
  int hd = tid>>5;
  const float* ar = attnf + ((b*NHD+hd)*NN+qi)*NN;
  float acc=0.f;
  for (int j=0;j<NN;j++) acc += ar[j]*v[(b*NN+j)*HH+tid];
  c[tid]=acc; __syncthreads();
  const float* wro = outW + tid*HH;
  float o = outb[tid];
  for (int m=0;m<HH;m++) o += c[m]*wro[m];
  float x = eig[row*HH+tid] + o;
  // LN
  buf[tid]=x; __syncthreads();
  for (int s2=64;s2>0;s2>>=1){ if(tid<s2) buf[tid]+=buf[tid+s2]; __syncthreads(); }
  float mean=buf[0]*(1.f/128.f); __syncthreads();
  float d=x-mean; buf[tid]=d*d; __syncthreads();
  for (int s2=64;s2>0;s2>>=1){ if(tid<s2) buf[tid]+=buf[tid+s2]; __syncthreads(); }
  float var=buf[0]*(1.f/128.f);
  xm[tid]=d*rsqrtf(var+EPSV)*fng[tid]+fnb[tid];
  __syncthreads();
  const float* wr1=w1+tid*HH;
  float a1=b1[tid];
  for (int m=0;m<HH;m++) a1+=xm[m]*wr1[m];
  tt[tid]=gelu_f(a1); __syncthreads();
  const float* wr2=w2+tid*HH;
  float a2=b2[tid];
  for (int m=0;m<HH;m++) a2+=tt[m]*wr2[m];
  eig[row*HH+tid]=x+a2;
}

__global__ void k_dec(const float* __restrict__ eig, const float* dW, const float* db,
                      float* __restrict__ newe, float* __restrict__ outp){
  int b = blockIdx.x, n = threadIdx.x;
  __shared__ float w[NHD*HH];
  for (int i=n;i<NHD*HH;i+=128) w[i]=dW[i];
  __syncthreads();
  float acc[NHD];
  #pragma unroll
  for (int kk=0;kk<NHD;kk++) acc[kk]=db[kk];
  const float* er = eig + (b*NN+n)*HH;
  for (int h2=0;h2<HH;h2++){
    float ev = er[h2];
    #pragma unroll
    for (int kk=0;kk<NHD;kk++) acc[kk]+=ev*w[kk*HH+h2];
  }
  #pragma unroll
  for (int kk=0;kk<NHD;kk++){
    int idx=(b*NHD+kk)*NN+n; newe[idx]=acc[kk];
    outp[8 + idx]=acc[kk];  // new_e at element offset 8
  }
}

// ---------------- bases ----------------

__global__ void k_filters(const float* __restrict__ u, const float* __restrict__ newe,
                          float* __restrict__ filt){
  int b = blockIdx.x, n0 = blockIdx.y*16, p0 = blockIdx.z*16;
  int tx = threadIdx.x, ty = threadIdx.y; int tid = ty*16+tx;
  __shared__ float un[16][17], upt[16][17], wk[4][16];
  float acc[4]={0.f,0.f,0.f,0.f};
  for (int mt=0; mt<8; mt++){
    __syncthreads();
    un[ty][tx]  = u[(b*NN+n0+ty)*NN + mt*16+tx];
    upt[tx][ty] = u[(b*NN+p0+ty)*NN + mt*16+tx];
    if (tid<64) wk[tid>>4][tid&15] = newe[(b*NHD+(tid>>4))*NN + mt*16 + (tid&15)];
    __syncthreads();
    #pragma unroll
    for (int mm=0;mm<16;mm++){
      float pr = un[ty][mm]*upt[mm][tx];
      #pragma unroll
      for (int kk=0;kk<4;kk++) acc[kk] += pr*wk[kk][mm];
    }
  }
  float4 o; o.x=acc[0];o.y=acc[1];o.z=acc[2];o.w=acc[3];
  *(float4*)&filt[((b*NN+n0+ty)*NN+p0+tx)*4] = o;
}

// convert fe2W (16384) + preW (4*16384) to bf16 once; also zero stats accumulators
__global__ void k_cvtw(const float* __restrict__ fe2W, const float* __restrict__ preW,
                       ushortt* __restrict__ wbf, float* __restrict__ gs){
  int idx = blockIdx.x*256 + threadIdx.x;
  if (idx < 2048) gs[idx] = 0.f;
  if (idx >= 81920) return;
  float v = (idx < 16384) ? fe2W[idx] : preW[idx - 16384];
  wbf[idx] = f2us(v);
}

// bases = gelu(gelu(in5@fe1W^T+b1)@fe2W^T+b2); A-fragments in registers, C staged
// through LDS for coalesced 8B global stores (round-5 epilogue was 2B-scattered).
__global__ __launch_bounds__(256) void k_fe2(const float* __restrict__ filt,
    const float* __restrict__ w1g, const float* __restrict__ b1g,
    const ushortt* __restrict__ w2bf, const float* __restrict__ b2g,
    bf16* __restrict__ bases){
  int bi = blockIdx.x;            // b*128 + n
  int nloc = bi & 127;
  int tid = threadIdx.x;
  int lane = tid & 63, w = tid >> 6, quad = lane >> 4, l15 = lane & 15;
  __shared__ alignas(16) ushortt sT[128*132];   // stride 132: 8B-aligned rows, quads hit distinct banks
  __shared__ float4 sF[128];
  __shared__ float w1[640], b1s[128], b2s[128];
  if (tid < 128) sF[tid] = ((const float4*)filt)[bi*128 + tid];
  for (int i = tid; i < 640; i += 256) w1[i] = w1g[i];
  if (tid < 128){ b1s[tid] = b1g[tid]; b2s[tid] = b2g[tid]; }
  __syncthreads();
  float4 f4[2]; float dg[2];
  #pragma unroll
  for (int mt=0;mt<2;mt++){
    int r = w*32 + mt*16 + l15;
    f4[mt] = sF[r];
    dg[mt] = (r == nloc) ? 1.0f : 0.0f;
  }
  f32x4 acc[2][8];
  #pragma unroll
  for (int mt=0;mt<2;mt++)
    #pragma unroll
    for (int nt=0;nt<8;nt++) acc[mt][nt] = (f32x4){0.f,0.f,0.f,0.f};
  for (int kk = 0; kk < 128; kk += 32){
    bf16x8 af[2];
    #pragma unroll
    for (int mt=0;mt<2;mt++){
      #pragma unroll
      for (int j=0;j<8;j++){
        int m = kk + quad*8 + j;
        float a = b1s[m] + w1[m*5]*dg[mt] + w1[m*5+1]*f4[mt].x + w1[m*5+2]*f4[mt].y
                + w1[m*5+3]*f4[mt].z + w1[m*5+4]*f4[mt].w;
        af[mt][j] = (short)f2us(gelu_f(a));
      }
    }
    bf16x8 bfr[8];
    #pragma unroll
    for (int nt=0;nt<8;nt++) bfr[nt] = *(const bf16x8*)&w2bf[(nt*16+l15)*128 + kk + quad*8];
    #pragma unroll
    for (int mt=0;mt<2;mt++)
      #pragma unroll
      for (int nt=0;nt<8;nt++)
        acc[mt][nt] = __builtin_amdgcn_mfma_f32_16x16x32_bf16(af[mt], bfr[nt], acc[mt][nt], 0, 0, 0);
  }
  #pragma unroll
  for (int mt=0;mt<2;mt++)
    #pragma unroll
    for (int nt=0;nt<8;nt++){
      int h = nt*16 + l15;
      float bb = b2s[h];
      #pragma unroll
      for (int reg=0;reg<4;reg++){
        int pr = w*32 + mt*16 + quad*4 + reg;
        sT[pr*132 + h] = f2us(gelu_f(acc[mt][nt][reg] + bb));
      }
    }
  __syncthreads();
  ushort4* gout = (ushort4*)(bases + (size_t)bi*16384);
  for (int idx = tid; idx < 4096; idx += 256){
    int row = idx >> 5, seg = idx & 31;
    gout[idx] = *(const ushort4*)&sT[row*132 + seg*4];
  }
}

// ---------------- message passing ----------------

__global__ void k_xfinit(const float* __restrict__ aemb, const int* __restrict__ nf,
                         float* __restrict__ xf){
  int idx = blockIdx.x*256+threadIdx.x;
  int node = idx >> 7, h2 = idx & 127;
  xf[idx] = aemb[nf[node]*HH + h2];
}

// per-layer: xfW = xf @ preW^T (MFMA, blocks 0..7); bondW[e] = bond_emb[e]@preW^T + preb (block 8)
__global__ __launch_bounds__(256) void k_xwl(const float* __restrict__ xf,
    const ushortt* __restrict__ wbfl, const float* __restrict__ bemb,
    const float* __restrict__ pb, float* __restrict__ xfW, float* __restrict__ bondW){
  int blk = blockIdx.x;
  int tid = threadIdx.x;
  if (blk == 8){
    for (int idx = tid; idx < 1280; idx += 256){
      int e2 = idx >> 7, h = idx & 127;
      const float* br = bemb + e2*128;
      const ushortt* wr = wbfl + h*128;
      float acc = pb[h];
      for (int m=0;m<128;m++) acc += br[m]*us2f(wr[m]);
      bondW[idx] = acc;
    }
    return;
  }
  int lane = tid & 63, w = tid >> 6, quad = lane >> 4, l15 = lane & 15;
  __shared__ alignas(16) ushortt sA[128*136];
  for (int idx = tid; idx < 4096; idx += 256){
    int r = idx >> 5, c = idx & 31;
    float4 xv = ((const float4*)xf)[(blk*128 + r)*32 + c];
    ushort4 o;
    o.x=f2us(xv.x); o.y=f2us(xv.y); o.z=f2us(xv.z); o.w=f2us(xv.w);
    *(ushort4*)&sA[r*136 + c*4] = o;
  }
  __syncthreads();
  f32x4 acc[2][8];
  #pragma unroll
  for (int mt=0;mt<2;mt++)
    #pragma unroll
    for (int nt=0;nt<8;nt++) acc[mt][nt] = (f32x4){0.f,0.f,0.f,0.f};
  #pragma unroll
  for (int kk = 0; kk < 128; kk += 32){
    bf16x8 af[2], bfr[8];
    #pragma unroll
    for (int mt=0;mt<2;mt++) af[mt] = *(const bf16x8*)&sA[(w*32+mt*16+l15)*136 + kk + quad*8];
    #pragma unroll
    for (int nt=0;nt<8;nt++) bfr[nt] = *(const bf16x8*)&wbfl[(nt*16+l15)*128 + kk + quad*8];
    #pragma unroll
    for (int mt=0;mt<2;mt++)
      #pragma unroll
      for (int nt=0;nt<8;nt++)
        acc[mt][nt] = __builtin_amdgcn_mfma_f32_16x16x32_bf16(af[mt], bfr[nt], acc[mt][nt], 0, 0, 0);
  }
  #pragma unroll
  for (int mt=0;mt<2;mt++)
    #pragma unroll
    for (int nt=0;nt<8;nt++){
      int h = nt*16 + l15;
      #pragma unroll
      for (int reg=0;reg<4;reg++){
        int pr = w*32 + mt*16 + quad*4 + reg;
        xfW[(blk*128 + pr)*128 + h] = acc[mt][nt][reg];
      }
    }
}

// per-edge elementwise: aggr[j,h] = sum_i gelu(xfW[i,h]+bondW[ef[i,j],h]) * bases[i,j,h]
// NOTE: bases is exactly symmetric in (i,j) (filters einsum + eye are symmetric,
// bitwise-identical op order), so we read bases[b][j][i][h] -> contiguous 32 KB/block.
__global__ __launch_bounds__(256) void k_edge(const float* __restrict__ xfin, float* __restrict__ xfout,
    const bf16* __restrict__ bases, const float* __restrict__ xfW,
    const float* __restrict__ bondW, const int* __restrict__ ef,
    const int* __restrict__ length){
  int bj = blockIdx.x; int b = bj >> 7, j = bj & 127;
  int len = length[b];
  int tid = threadIdx.x; int h = tid & 127, ih = tid >> 7;
  __shared__ float sBW[10][128];
  __shared__ int sEf[128];
  __shared__ float part[2][128];
  for (int idx = tid; idx < 1280; idx += 256) sBW[idx>>7][idx&127] = bondW[idx];
  if (tid < 128) sEf[tid] = ef[(b*NN + tid)*NN + j];
  __syncthreads();
  float agg = 0.f;
  if (j < len){
    const float* xwb = xfW + b*NN*HH + h;
    const bf16* bb = bases + ((size_t)b*NN + j)*NN*HH + h;   // symmetric: row j, walk i
    for (int i = ih; i < len; i += 2){
      float vv = gelu_f(xwb[i*128] + sBW[sEf[i]][h]);
      agg += vv * b2f(bb[i*128]);
    }
  }
  part[ih][h] = agg; __syncthreads();
  if (tid < 128){
    int o = (b*NN + j)*HH + tid;
    xfout[o] = xfin[o] + part[0][tid] + part[1][tid];
  }
}

// g1 GEMM + masked partial BN stats (8 rows/block)
__global__ __launch_bounds__(256) void k_g1s(const float* __restrict__ xf,
    const float* __restrict__ w, const float* __restrict__ bias,
    const int* __restrict__ length, float* __restrict__ t1,
    float* __restrict__ gsum, float* __restrict__ gsq){
  int blk = blockIdx.x; int tid = threadIdx.x;
  int f = tid & 127, rh = tid >> 7;
  __shared__ float sx[8][128];
  __shared__ float red1[2][128], red2[2][128];
  int r0 = blk*8;
  for (int idx = tid; idx < 1024; idx += 256){
    int r = idx >> 7, m = idx & 127;
    sx[r][m] = xf[(r0+r)*128 + m];
  }
  __syncthreads();
  const float* wr = w + f*128;
  float bsv = bias[f];
  float s=0.f, s2=0.f;
  for (int rr = rh*4; rr < rh*4+4; rr++){
    int rg = r0 + rr; int b = rg >> 7, n = rg & 127;
    float acc = bsv;
    for (int m=0;m<128;m++) acc += sx[rr][m]*wr[m];
    t1[rg*128+f] = acc;
    if (n < length[b]){ s += acc; s2 += acc*acc; }
  }
  red1[rh][f]=s; red2[rh][f]=s2; __syncthreads();
  if (tid < 128){
    atomicAdd(&gsum[tid], red1[0][tid]+red1[1][tid]);
    atomicAdd(&gsq[tid],  red2[0][tid]+red2[1][tid]);
  }
}

// finalize BN1 + relu + g2 GEMM + partial BN2 stats
__global__ __launch_bounds__(256) void k_g2s(const float* __restrict__ t1,
    const float* __restrict__ gsum1, const float* __restrict__ gsq1,
    const float* __restrict__ g1, const float* __restrict__ bb1,
    const float* __restrict__ w2, const float* __restrict__ bias2,
    const int* __restrict__ length, float* __restrict__ t2,
    float* __restrict__ gsum2, float* __restrict__ gsq2){
  int blk = blockIdx.x; int tid = threadIdx.x;
  int f = tid & 127, rh = tid >> 7;
  __shared__ float sy[8][128];
  __shared__ float red1[2][128], red2[2][128];
  int r0 = blk*8;
  float cnt = 0.f;
  for (int b=0;b<BB;b++) cnt += (float)length[b];
  float mu = gsum1[f]/cnt;
  float var = gsq1[f]/cnt - mu*mu;
  float istd = rsqrtf(fmaxf(var,0.0f)+EPSV);
  float gg = g1[f], bbv = bb1[f];
  for (int idx = tid; idx < 1024; idx += 256){
    int r = idx >> 7;            // m == f for this thread (stride 256 keeps low 7 bits)
    float x = t1[(r0+r)*128 + f];
    float y = (x-mu)*istd*gg + bbv;
    sy[r][f] = fmaxf(y, 0.0f);
  }
  __syncthreads();
  const float* wr = w2 + f*128;
  float bsv = bias2[f];
  float s=0.f, s2=0.f;
  for (int rr = rh*4; rr < rh*4+4; rr++){
    int rg = r0 + rr; int b = rg >> 7, n = rg & 127;
    float acc = bsv;
    for (int m=0;m<128;m++) acc += sy[rr][m]*wr[m];
    t2[rg*128+f] = acc;
    if (n < length[b]){ s += acc; s2 += acc*acc; }
  }
  red1[rh][f]=s; red2[rh][f]=s2; __syncthreads();
  if (tid < 128){
    atomicAdd(&gsum2[tid], red1[0][tid]+red1[1][tid]);
    atomicAdd(&gsq2[tid],  red2[0][tid]+red2[1][tid]);
  }
}

// finalize BN2 + relu + residual add
__global__ void k_apply2(const float* __restrict__ t2, const float* __restrict__ gsum2,
    const float* __restrict__ gsq2, const float* __restrict__ g2,
    const float* __restrict__ bb2, const int* __restrict__ length,
    float* __restrict__ xf){
  int idx = blockIdx.x*256+threadIdx.x;
  int f = idx & 127;
  float cnt = 0.f;
  for (int b=0;b<BB;b++) cnt += (float)length[b];
  float mu = gsum2[f]/cnt;
  float var = gsq2[f]/cnt - mu*mu;
  float istd = rsqrtf(fmaxf(var,0.0f)+EPSV);
  float x = t2[idx];
  float y = (x-mu)*istd*g2[f]+bb2[f];
  xf[idx] += fmaxf(y,0.0f);
}

__global__ void k_pool(const float* __restrict__ xf, const int* __restrict__ length,
                       const float* lw, const float* lb, float* __restrict__ outp){
  int b = blockIdx.x, tid=threadIdx.x;
  int len = length[b];
  float s=0.f;
  for (int n2=0;n2<len;n2++) s += xf[(b*NN+n2)*HH+tid];
  s /= (float)len;
  __shared__ float red[128];
  red[tid]=s*lw[tid]; __syncthreads();
  for (int st=64;st>0;st>>=1){ if(tid<st) red[tid]+=red[tid+st]; __syncthreads(); }
  if (tid==0) outp[b]=red[0]+lb[0];
}

// ---------------- host ----------------

extern "C" void kernel_launch(void* const* d_in, const int* in_sizes, int n_in,
                              void* d_out, int out_size, void* d_ws, size_t ws_size,
                              hipStream_t stream) {
  (void)in_sizes; (void)n_in; (void)out_size; (void)ws_size;
  const float* e        = (const float*)d_in[0];
  const float* u        = (const float*)d_in[1];
  const float* atom_emb = (const float*)d_in[2];
  const float* bond_emb = (const float*)d_in[3];
  const float* eigw_W   = (const float*)d_in[4];
  const float* eigw_b   = (const float*)d_in[5];
  const float* mng      = (const float*)d_in[6];
  const float* mnb      = (const float*)d_in[7];
  const float* qkvW     = (const float*)d_in[8];
  const float* qkvb     = (const float*)d_in[9];
  const float* outW     = (const float*)d_in[10];
  const float* outb     = (const float*)d_in[11];
  const float* fng      = (const float*)d_in[12];
  const float* fnb      = (const float*)d_in[13];
  const float* ffn1W    = (const float*)d_in[14];
  const float* ffn1b    = (const float*)d_in[15];
  const float* ffn2W    = (const float*)d_in[16];
  const float* ffn2b    = (const float*)d_in[17];
  const float* decW     = (const float*)d_in[18];
  const float* decb     = (const float*)d_in[19];
  const float* fe1W     = (const float*)d_in[20];
  const float* fe1b     = (const float*)d_in[21];
  const float* fe2W     = (const float*)d_in[22];
  const float* fe2b     = (const float*)d_in[23];
  const float* preW     = (const float*)d_in[24];
  const float* preb     = (const float*)d_in[25];
  const float* f1W      = (const float*)d_in[26];
  const float* f1b      = (const float*)d_in[27];
  const float* bn1g     = (const float*)d_in[28];
  const float* bn1b     = (const float*)d_in[29];
  const float* f2W      = (const float*)d_in[30];
  const float* f2b      = (const float*)d_in[31];
  const float* bn2g     = (const float*)d_in[32];
  const float* bn2b     = (const float*)d_in[33];
  const float* linW     = (const float*)d_in[34];
  const float* linb     = (const float*)d_in[35];
  const int* nodef      = (const int*)d_in[36];
  const int* edgef      = (const int*)d_in[37];
  const int* length     = (const int*)d_in[38];

  float* outp = (float*)d_out;   // h[8] ++ new_e[4096] ++ attn[524288], f32

  char* p = (char*)d_ws;
  auto alloc = [&](size_t bytes)->void*{ void* r=(void*)p; p += (bytes+255)&~(size_t)255; return r; };
  const int TOK = BB*NN*HH;           // 131072
  float* eig   = (float*)alloc(TOK*4);
  float* q     = (float*)alloc(TOK*4);
  float* k     = (float*)alloc(TOK*4);
  float* v     = (float*)alloc(TOK*4);
  float* attnf = (float*)alloc((size_t)BB*NHD*NN*NN*4);
  float* newe  = (float*)alloc(BB*NHD*NN*4);
  float* filt  = (float*)alloc((size_t)BB*NN*NN*4*4);
  bf16*  bases = (bf16*) alloc((size_t)BB*NN*NN*HH*2);
  float* xf0   = (float*)alloc(TOK*4);
  float* xf1   = (float*)alloc(TOK*4);
  float* t1    = (float*)alloc(TOK*4);
  float* t2    = (float*)alloc(TOK*4);
  float* xfW   = (float*)alloc(TOK*4);
  float* bondW = (float*)alloc(10*128*4);
  float* gs    = (float*)alloc(2048*4);     // per-layer BN stat accumulators (4 layers x 512)
  ushortt* wbf = (ushortt*)alloc(81920*2);  // fe2W bf16 + preW[4] bf16

  k_cvtw<<<320, 256, 0, stream>>>(fe2W, preW, wbf, gs);

  // front end
  k_fe_a<<<BB*NN, 128, 0, stream>>>(e, eigw_W, eigw_b, mng, mnb, qkvW, qkvb, eig, q, k, v);
  k_attn<<<BB*NHD*NN, 128, 0, stream>>>(q, k, length, attnf, outp);
  k_fe_c<<<BB*NN, 128, 0, stream>>>(attnf, v, outW, outb, fng, fnb,
                                    ffn1W, ffn1b, ffn2W, ffn2b, eig);
  k_dec<<<BB, 128, 0, stream>>>(eig, decW, decb, newe, outp);

  // bases
  k_filters<<<dim3(BB,8,8), dim3(16,16), 0, stream>>>(u, newe, filt);
  k_fe2<<<BB*NN, 256, 0, stream>>>(filt, fe1W, fe1b, wbf, fe2b, bases);

  // message passing
  k_xfinit<<<TOK/256, 256, 0, stream>>>(atom_emb, nodef, xf0);
  float* src = xf0; float* dst = xf1;
  for (int l=0;l<LAY;l++){
    const ushortt* wbfl = wbf + 16384 + l*16384;
    float* gsl = gs + l*512;
    k_xwl<<<9, 256, 0, stream>>>(src, wbfl, bond_emb, preb + l*HH, xfW, bondW);
    k_edge<<<BB*NN, 256, 0, stream>>>(src, dst, bases, xfW, bondW, edgef, length);
    k_g1s<<<128, 256, 0, stream>>>(dst, f1W + (size_t)l*HH*HH, f1b + l*HH, length,
                                   t1, gsl, gsl+128);
    k_g2s<<<128, 256, 0, stream>>>(t1, gsl, gsl+128, bn1g + l*HH, bn1b + l*HH,
                                   f2W + (size_t)l*HH*HH, f2b + l*HH, length,
                                   t2, gsl+256, gsl+384);
    k_apply2<<<512, 256, 0, stream>>>(t2, gsl+256, gsl+384, bn2g + l*HH, bn2b + l*HH,
                                      length, dst);
    float* tmp = src; src = dst; dst = tmp;
  }
  // after loop final xf is in src (xf0)
  k_pool<<<BB, 128, 0, stream>>>(src, length, linW, linb, outp);
}